// Round 1
// baseline (589.746 us; speedup 1.0000x reference)
//
#include <hip/hip_runtime.h>
#include <hip/hip_bf16.h>
#include <math.h>

// Problem constants (from reference)
#define NN 50000
#define EE 800000
#define ET 850000   // EE + NN self loops
#define NFEATS 256
#define NHIDS 32
#define NHEADS 8
#define NOUT 128

// ---------------------------------------------------------------------------
// CSR build: histogram -> scan -> scatter
// ---------------------------------------------------------------------------
__global__ void k_hist(const int* __restrict__ ei, int* __restrict__ deg) {
    int e = blockIdx.x * blockDim.x + threadIdx.x;
    if (e >= ET) return;
    int d = (e < EE) ? ei[EE + e] : (e - EE);
    atomicAdd(&deg[d], 1);
}

__global__ void k_scan_block(const int* __restrict__ deg, int* __restrict__ offsets,
                             int* __restrict__ bsum, int n) {
    __shared__ int lds[1024];
    int i = blockIdx.x * 1024 + threadIdx.x;
    int v = (i < n) ? deg[i] : 0;
    lds[threadIdx.x] = v;
    __syncthreads();
    for (int off = 1; off < 1024; off <<= 1) {
        int t = 0;
        if ((int)threadIdx.x >= off) t = lds[threadIdx.x - off];
        __syncthreads();
        lds[threadIdx.x] += t;
        __syncthreads();
    }
    if (i < n) offsets[i] = lds[threadIdx.x] - v;   // exclusive within block
    if (threadIdx.x == 1023) bsum[blockIdx.x] = lds[1023];
}

__global__ void k_scan_bsums(int* __restrict__ bsum, int nb) {
    int t = threadIdx.x;                 // single block, 64 threads, nb <= 64
    int v0 = (t < nb) ? bsum[t] : 0;
    int v = v0;
    for (int off = 1; off < 64; off <<= 1) {
        int u = __shfl_up(v, off, 64);
        if (t >= off) v += u;
    }
    if (t < nb) bsum[t] = v - v0;        // exclusive block offsets
}

__global__ void k_add_off(int* __restrict__ offsets, const int* __restrict__ bsum,
                          int n, int total) {
    int i = blockIdx.x * blockDim.x + threadIdx.x;
    if (i < n) offsets[i] += bsum[i >> 10];
    if (i == 0) offsets[n] = total;
}

__global__ void k_scatter(const int* __restrict__ ei, const int* __restrict__ offsets,
                          int* __restrict__ cursor, int* __restrict__ sorted) {
    int e = blockIdx.x * blockDim.x + threadIdx.x;
    if (e >= ET) return;
    int d = (e < EE) ? ei[EE + e] : (e - EE);
    int pos = offsets[d] + atomicAdd(&cursor[d], 1);
    sorted[pos] = e;
}

// ---------------------------------------------------------------------------
// fp32 GEMM: C[m][n] = sum_k A[m][k] * B[n][k]   (A: MxK, B: NoutxK, both row major)
// ---------------------------------------------------------------------------
#define BM 64
#define BN 64
#define BK 32
__global__ __launch_bounds__(256) void gemm_tn(const float* __restrict__ A,
                                               const float* __restrict__ B,
                                               float* __restrict__ C,
                                               int M, int Nout, int K) {
    __shared__ float As[BK][BM + 1];
    __shared__ float Bs[BK][BN + 1];
    int tid = threadIdx.x;
    int tx = tid & 15, ty = tid >> 4;
    int m0 = blockIdx.x * BM, n0 = blockIdx.y * BN;
    float acc[4][4] = {};
    for (int k0 = 0; k0 < K; k0 += BK) {
        int c4 = tid & 7;       // float4 column within BK
        int r = tid >> 3;       // 0..31
        for (int rr = r; rr < BM; rr += 32) {
            int gm = m0 + rr;
            float4 v = make_float4(0.f, 0.f, 0.f, 0.f);
            if (gm < M) v = *(const float4*)(A + (size_t)gm * K + k0 + c4 * 4);
            As[c4 * 4 + 0][rr] = v.x; As[c4 * 4 + 1][rr] = v.y;
            As[c4 * 4 + 2][rr] = v.z; As[c4 * 4 + 3][rr] = v.w;
        }
        for (int rr = r; rr < BN; rr += 32) {
            int gn = n0 + rr;
            float4 v = *(const float4*)(B + (size_t)gn * K + k0 + c4 * 4);
            Bs[c4 * 4 + 0][rr] = v.x; Bs[c4 * 4 + 1][rr] = v.y;
            Bs[c4 * 4 + 2][rr] = v.z; Bs[c4 * 4 + 3][rr] = v.w;
        }
        __syncthreads();
#pragma unroll
        for (int k = 0; k < BK; ++k) {
            float a[4], b[4];
#pragma unroll
            for (int i = 0; i < 4; i++) a[i] = As[k][ty * 4 + i];
#pragma unroll
            for (int j = 0; j < 4; j++) b[j] = Bs[k][tx * 4 + j];
#pragma unroll
            for (int i = 0; i < 4; i++)
#pragma unroll
                for (int j = 0; j < 4; j++) acc[i][j] += a[i] * b[j];
        }
        __syncthreads();
    }
    for (int i = 0; i < 4; i++) {
        int gm = m0 + ty * 4 + i;
        if (gm >= M) continue;
        float4 v = make_float4(acc[i][0], acc[i][1], acc[i][2], acc[i][3]);
        *(float4*)(C + (size_t)gm * Nout + n0 + tx * 4) = v;
    }
}

// ---------------------------------------------------------------------------
// attention logits
// ---------------------------------------------------------------------------
__global__ __launch_bounds__(64) void k_att1(const float* __restrict__ h1,
                                             const float* __restrict__ aS,
                                             const float* __restrict__ aD,
                                             float* __restrict__ als,
                                             float* __restrict__ ald) {
    int n = blockIdx.x;
    int t = threadIdx.x;
    const float* row = h1 + (size_t)n * 256;
#pragma unroll
    for (int q = 0; q < 4; q++) {
        int c = q * 64 + t;
        float hv = row[c];
        float vs = hv * aS[c];
        float vd = hv * aD[c];
#pragma unroll
        for (int off = 16; off >= 1; off >>= 1) {
            vs += __shfl_down(vs, off, 32);
            vd += __shfl_down(vd, off, 32);
        }
        if ((t & 31) == 0) {
            int head = q * 2 + (t >> 5);
            als[n * 8 + head] = vs;
            ald[n * 8 + head] = vd;
        }
    }
}

__global__ __launch_bounds__(64) void k_att2(const float* __restrict__ h2,
                                             const float* __restrict__ aS,
                                             const float* __restrict__ aD,
                                             float* __restrict__ als,
                                             float* __restrict__ ald) {
    int n = blockIdx.x;
    int t = threadIdx.x;
    const float* row = h2 + (size_t)n * 128;
    float hv0 = row[t], hv1 = row[64 + t];
    float vs = hv0 * aS[t] + hv1 * aS[64 + t];
    float vd = hv0 * aD[t] + hv1 * aD[64 + t];
#pragma unroll
    for (int off = 32; off >= 1; off >>= 1) {
        vs += __shfl_down(vs, off, 64);
        vd += __shfl_down(vd, off, 64);
    }
    if (t == 0) { als[n] = vs; ald[n] = vd; }
}

// ---------------------------------------------------------------------------
// Layer 1 aggregation: one block (256 thr) per destination node.
// thread tid -> (head = tid>>5, comp = tid&31) == output component tid.
// ---------------------------------------------------------------------------
__global__ __launch_bounds__(256) void k_aggregate1(
    const float* __restrict__ h1, const float* __restrict__ als,
    const float* __restrict__ ald, const int* __restrict__ offsets,
    const int* __restrict__ sorted, const int* __restrict__ ei,
    const float* __restrict__ b1, float* __restrict__ out1) {
    int n = blockIdx.x;
    int tid = threadIdx.x;
    int head = tid >> 5, lane = tid & 31;
    int base = offsets[n];
    int deg = offsets[n + 1] - base;
    __shared__ float m_s[8];
    __shared__ float w_s[32][8];
    __shared__ int s_s[32];

    float aldv = ald[n * 8 + head];
    float mloc = -1e30f;
    for (int i = lane; i < deg; i += 32) {
        int e = sorted[base + i];
        int s = (e < EE) ? ei[e] : (e - EE);
        float v = als[s * 8 + head] + aldv;
        v = (v >= 0.f) ? v : 0.2f * v;
        mloc = fmaxf(mloc, v);
    }
#pragma unroll
    for (int off = 16; off >= 1; off >>= 1)
        mloc = fmaxf(mloc, __shfl_xor(mloc, off, 32));
    if (lane == 0) m_s[head] = mloc;
    __syncthreads();

    int fi = tid >> 3, fh = tid & 7;     // fill roles: 32 edges x 8 heads
    float aldf = ald[n * 8 + fh];
    float mf = m_s[fh];
    float acc = 0.f, dsum = 0.f;
    for (int chunk = 0; chunk < deg; chunk += 32) {
        int len = min(32, deg - chunk);
        if (fi < len) {
            int e = sorted[base + chunk + fi];
            int s = (e < EE) ? ei[e] : (e - EE);
            if (fh == 0) s_s[fi] = s;
            float v = als[s * 8 + fh] + aldf;
            v = (v >= 0.f) ? v : 0.2f * v;
            w_s[fi][fh] = expf(v - mf);
        }
        __syncthreads();
        for (int i = 0; i < len; i++) {
            float w = w_s[i][head];
            int s = s_s[i];
            acc += w * h1[(size_t)s * 256 + tid];
            dsum += w;
        }
        __syncthreads();
    }
    float r = acc / (dsum + 1e-16f) + b1[tid];
    out1[(size_t)n * 256 + tid] = (r >= 0.f) ? r : 0.2f * r;  // module LeakyReLU
}

// ---------------------------------------------------------------------------
// Layer 2 aggregation: one block (128 thr) per destination node, 1 head, C=128
// ---------------------------------------------------------------------------
__global__ __launch_bounds__(128) void k_aggregate2(
    const float* __restrict__ h2, const float* __restrict__ als,
    const float* __restrict__ ald, const int* __restrict__ offsets,
    const int* __restrict__ sorted, const int* __restrict__ ei,
    const float* __restrict__ b2, float* __restrict__ out) {
    int n = blockIdx.x;
    int tid = threadIdx.x;
    int base = offsets[n];
    int deg = offsets[n + 1] - base;
    __shared__ float w_s[128];
    __shared__ int s_s[128];
    __shared__ float red[2];

    float aldv = ald[n];
    float mloc = -1e30f;
    for (int i = tid; i < deg; i += 128) {
        int e = sorted[base + i];
        int s = (e < EE) ? ei[e] : (e - EE);
        float v = als[s] + aldv;
        v = (v >= 0.f) ? v : 0.2f * v;
        mloc = fmaxf(mloc, v);
    }
#pragma unroll
    for (int off = 32; off >= 1; off >>= 1)
        mloc = fmaxf(mloc, __shfl_xor(mloc, off, 64));
    if ((tid & 63) == 0) red[tid >> 6] = mloc;
    __syncthreads();
    float m = fmaxf(red[0], red[1]);

    float acc = 0.f, dsum = 0.f;
    for (int chunk = 0; chunk < deg; chunk += 128) {
        int len = min(128, deg - chunk);
        if (tid < len) {
            int e = sorted[base + chunk + tid];
            int s = (e < EE) ? ei[e] : (e - EE);
            s_s[tid] = s;
            float v = als[s] + aldv;
            v = (v >= 0.f) ? v : 0.2f * v;
            w_s[tid] = expf(v - m);
        }
        __syncthreads();
        for (int i = 0; i < len; i++) {
            float w = w_s[i];
            acc += w * h2[(size_t)s_s[i] * 128 + tid];
            dsum += w;
        }
        __syncthreads();
    }
    out[(size_t)n * 128 + tid] = acc / (dsum + 1e-16f) + b2[tid];
}

// ---------------------------------------------------------------------------
extern "C" void kernel_launch(void* const* d_in, const int* in_sizes, int n_in,
                              void* d_out, int out_size, void* d_ws, size_t ws_size,
                              hipStream_t stream) {
    const int* ei = (const int*)d_in[0];         // [2, EE] int32
    const float* x = (const float*)d_in[1];      // [N, 256]
    const float* W1 = (const float*)d_in[2];     // [256, 256]
    const float* aS1 = (const float*)d_in[3];    // [8, 32]
    const float* aD1 = (const float*)d_in[4];    // [8, 32]
    const float* b1 = (const float*)d_in[5];     // [256]
    const float* W2 = (const float*)d_in[6];     // [128, 256]
    const float* aS2 = (const float*)d_in[7];    // [1, 128]
    const float* aD2 = (const float*)d_in[8];    // [1, 128]
    const float* b2 = (const float*)d_in[9];     // [128]
    float* out = (float*)d_out;

    char* w = (char*)d_ws;
    auto alloc = [&](size_t bytes) {
        char* p = w;
        w += (bytes + 255) & ~(size_t)255;
        return p;
    };
    float* h1   = (float*)alloc((size_t)NN * 256 * 4);   // also reused as h2
    float* out1 = (float*)alloc((size_t)NN * 256 * 4);
    float* als1 = (float*)alloc((size_t)NN * 8 * 4);     // reused as als2
    float* ald1 = (float*)alloc((size_t)NN * 8 * 4);     // reused as ald2
    int* deg     = (int*)alloc((size_t)(NN + 1) * 4);
    int* offsets = (int*)alloc((size_t)(NN + 1) * 4);
    int* cursor  = (int*)alloc((size_t)NN * 4);
    int* sorted  = (int*)alloc((size_t)ET * 4);
    int* bsum    = (int*)alloc(64 * 4);
    float* h2 = h1;
    float* als2 = als1;
    float* ald2 = ald1;

    const int nb = (NN + 1023) / 1024;

    hipMemsetAsync(deg, 0, (size_t)NN * 4, stream);
    hipMemsetAsync(cursor, 0, (size_t)NN * 4, stream);

    // CSR build
    k_hist<<<(ET + 255) / 256, 256, 0, stream>>>(ei, deg);
    k_scan_block<<<nb, 1024, 0, stream>>>(deg, offsets, bsum, NN);
    k_scan_bsums<<<1, 64, 0, stream>>>(bsum, nb);
    k_add_off<<<(NN + 255) / 256, 256, 0, stream>>>(offsets, bsum, NN, ET);
    k_scatter<<<(ET + 255) / 256, 256, 0, stream>>>(ei, offsets, cursor, sorted);

    // Layer 1
    gemm_tn<<<dim3((NN + BM - 1) / BM, 256 / BN), 256, 0, stream>>>(x, W1, h1, NN, 256, 256);
    k_att1<<<NN, 64, 0, stream>>>(h1, aS1, aD1, als1, ald1);
    k_aggregate1<<<NN, 256, 0, stream>>>(h1, als1, ald1, offsets, sorted, ei, b1, out1);

    // Layer 2
    gemm_tn<<<dim3((NN + BM - 1) / BM, 128 / BN), 256, 0, stream>>>(out1, W2, h2, NN, 128, 256);
    k_att2<<<NN, 64, 0, stream>>>(h2, aS2, aD2, als2, ald2);
    k_aggregate2<<<NN, 128, 0, stream>>>(h2, als2, ald2, offsets, sorted, ei, b2, out);
}

// Round 2
// 414.339 us; speedup vs baseline: 1.4233x; 1.4233x over previous
//
#include <hip/hip_runtime.h>
#include <hip/hip_bf16.h>
#include <math.h>

// Problem constants (from reference)
#define NN 50000
#define EE 800000
#define ET 850000   // EE + NN self loops
#define NFEATS 256
#define NHIDS 32
#define NHEADS 8
#define NOUT 128

typedef __attribute__((ext_vector_type(8))) short bf16x8;
typedef __attribute__((ext_vector_type(4))) float f32x4;

__device__ inline ushort f2bf(float x) {
    __hip_bfloat16 b = __float2bfloat16(x);   // RTN
    return *reinterpret_cast<ushort*>(&b);
}
__device__ inline float bf2f(ushort u) {
    unsigned v = ((unsigned)u) << 16;
    return __builtin_bit_cast(float, v);
}

// ---------------------------------------------------------------------------
// CSR build: histogram -> scan -> scatter
// ---------------------------------------------------------------------------
__global__ void k_hist(const int* __restrict__ ei, int* __restrict__ deg) {
    int e = blockIdx.x * blockDim.x + threadIdx.x;
    if (e >= ET) return;
    int d = (e < EE) ? ei[EE + e] : (e - EE);
    atomicAdd(&deg[d], 1);
}

__global__ void k_scan_block(const int* __restrict__ deg, int* __restrict__ offsets,
                             int* __restrict__ bsum, int n) {
    __shared__ int lds[1024];
    int i = blockIdx.x * 1024 + threadIdx.x;
    int v = (i < n) ? deg[i] : 0;
    lds[threadIdx.x] = v;
    __syncthreads();
    for (int off = 1; off < 1024; off <<= 1) {
        int t = 0;
        if ((int)threadIdx.x >= off) t = lds[threadIdx.x - off];
        __syncthreads();
        lds[threadIdx.x] += t;
        __syncthreads();
    }
    if (i < n) offsets[i] = lds[threadIdx.x] - v;   // exclusive within block
    if (threadIdx.x == 1023) bsum[blockIdx.x] = lds[1023];
}

__global__ void k_scan_bsums(int* __restrict__ bsum, int nb) {
    int t = threadIdx.x;                 // single block, 64 threads, nb <= 64
    int v0 = (t < nb) ? bsum[t] : 0;
    int v = v0;
    for (int off = 1; off < 64; off <<= 1) {
        int u = __shfl_up(v, off, 64);
        if (t >= off) v += u;
    }
    if (t < nb) bsum[t] = v - v0;        // exclusive block offsets
}

__global__ void k_add_off(int* __restrict__ offsets, const int* __restrict__ bsum,
                          int n, int total) {
    int i = blockIdx.x * blockDim.x + threadIdx.x;
    if (i < n) offsets[i] += bsum[i >> 10];
    if (i == 0) offsets[n] = total;
}

__global__ void k_scatter(const int* __restrict__ ei, const int* __restrict__ offsets,
                          int* __restrict__ cursor, int* __restrict__ sorted) {
    int e = blockIdx.x * blockDim.x + threadIdx.x;
    if (e >= ET) return;
    int d = (e < EE) ? ei[EE + e] : (e - EE);
    int pos = offsets[d] + atomicAdd(&cursor[d], 1);
    sorted[pos] = e;
}

// ---------------------------------------------------------------------------
// bf16x3 MFMA GEMM: C[m][n] = sum_k A[m][k]*B[n][k], fp32 in/out, K=256.
// Each fp32 split hi/lo bf16; acc += hi*hi + hi*lo + lo*hi (error ~2^-17).
// Block: 512 thr = 8 waves (2 x 4), tile 128 x TBN (TBN = full N: 256 or 128).
// LDS row stride 40 ushort (80 B = 5*16B): aligned b128 reads, banks spread
// over all 32 across 8 rows -> 2-way (free).
// ---------------------------------------------------------------------------
template <int TBN>
__global__ __launch_bounds__(512) void gemm_bf16x3(const float* __restrict__ A,
                                                   const float* __restrict__ Bw,
                                                   float* __restrict__ C, int M) {
    constexpr int K = 256;
    constexpr int WN = TBN / 4;    // wave n-tile: 64 or 32
    constexpr int NF = WN / 16;    // n-frags per wave: 4 or 2
    __shared__ ushort Ah[128][40], Al[128][40];
    __shared__ ushort Bh[TBN][40], Bl[TBN][40];

    int tid = threadIdx.x;
    int wid = tid >> 6, lane = tid & 63;
    int wm = wid >> 2, wn = wid & 3;          // 2 x 4 wave grid
    int m0 = blockIdx.x * 128;

    f32x4 acc[4][NF];
#pragma unroll
    for (int i = 0; i < 4; i++)
#pragma unroll
        for (int j = 0; j < NF; j++) acc[i][j] = (f32x4){0.f, 0.f, 0.f, 0.f};

    for (int k0 = 0; k0 < K; k0 += 32) {
        // stage A tile: 128 rows x 8 float4 = 1024 slots / 512 thr = 2 each
#pragma unroll
        for (int i = 0; i < 2; i++) {
            int s = tid + 512 * i;
            int r = s >> 3, c4 = s & 7;
            float4 v = make_float4(0.f, 0.f, 0.f, 0.f);
            if (m0 + r < M) v = *(const float4*)(A + (size_t)(m0 + r) * K + k0 + c4 * 4);
            ushort4 hi, lo;
            hi.x = f2bf(v.x); lo.x = f2bf(v.x - bf2f(hi.x));
            hi.y = f2bf(v.y); lo.y = f2bf(v.y - bf2f(hi.y));
            hi.z = f2bf(v.z); lo.z = f2bf(v.z - bf2f(hi.z));
            hi.w = f2bf(v.w); lo.w = f2bf(v.w - bf2f(hi.w));
            *(ushort4*)&Ah[r][c4 * 4] = hi;
            *(ushort4*)&Al[r][c4 * 4] = lo;
        }
        // stage B tile: TBN rows x 8 float4 slots
#pragma unroll
        for (int i = 0; i < TBN / 64; i++) {
            int s = tid + 512 * i;
            int r = s >> 3, c4 = s & 7;
            float4 v = *(const float4*)(Bw + (size_t)r * K + k0 + c4 * 4);
            ushort4 hi, lo;
            hi.x = f2bf(v.x); lo.x = f2bf(v.x - bf2f(hi.x));
            hi.y = f2bf(v.y); lo.y = f2bf(v.y - bf2f(hi.y));
            hi.z = f2bf(v.z); lo.z = f2bf(v.z - bf2f(hi.z));
            hi.w = f2bf(v.w); lo.w = f2bf(v.w - bf2f(hi.w));
            *(ushort4*)&Bh[r][c4 * 4] = hi;
            *(ushort4*)&Bl[r][c4 * 4] = lo;
        }
        __syncthreads();

        int koff = (lane >> 4) * 8;          // k-offset within BK=32
        int rsel = lane & 15;
        bf16x8 ah[4], al[4], bh[NF], bl[NF];
#pragma unroll
        for (int mf = 0; mf < 4; mf++) {
            int r = wm * 64 + mf * 16 + rsel;
            ah[mf] = *(const bf16x8*)&Ah[r][koff];
            al[mf] = *(const bf16x8*)&Al[r][koff];
        }
#pragma unroll
        for (int nf = 0; nf < NF; nf++) {
            int c = wn * WN + nf * 16 + rsel;
            bh[nf] = *(const bf16x8*)&Bh[c][koff];
            bl[nf] = *(const bf16x8*)&Bl[c][koff];
        }
#pragma unroll
        for (int mf = 0; mf < 4; mf++)
#pragma unroll
            for (int nf = 0; nf < NF; nf++) {
                acc[mf][nf] = __builtin_amdgcn_mfma_f32_16x16x32_bf16(ah[mf], bh[nf], acc[mf][nf], 0, 0, 0);
                acc[mf][nf] = __builtin_amdgcn_mfma_f32_16x16x32_bf16(ah[mf], bl[nf], acc[mf][nf], 0, 0, 0);
                acc[mf][nf] = __builtin_amdgcn_mfma_f32_16x16x32_bf16(al[mf], bh[nf], acc[mf][nf], 0, 0, 0);
            }
        __syncthreads();
    }

    // epilogue: C/D layout col = lane&15, row = (lane>>4)*4 + j
#pragma unroll
    for (int mf = 0; mf < 4; mf++) {
        int gr = m0 + wm * 64 + mf * 16 + (lane >> 4) * 4;
#pragma unroll
        for (int nf = 0; nf < NF; nf++) {
            int gc = wn * WN + nf * 16 + (lane & 15);
#pragma unroll
            for (int j = 0; j < 4; j++) {
                if (gr + j < M) C[(size_t)(gr + j) * TBN + gc] = acc[mf][nf][j];
            }
        }
    }
}

// ---------------------------------------------------------------------------
// attention logits (vectorized: float4 per lane)
// ---------------------------------------------------------------------------
__global__ __launch_bounds__(256) void k_att1v(const float* __restrict__ h1,
                                               const float* __restrict__ aS,
                                               const float* __restrict__ aD,
                                               float* __restrict__ als,
                                               float* __restrict__ ald) {
    int n = blockIdx.x * 4 + (threadIdx.x >> 6);   // wave per node
    int lane = threadIdx.x & 63;
    if (n >= NN) return;
    float4 h = *(const float4*)(h1 + (size_t)n * 256 + lane * 4);
    float4 s4 = *(const float4*)(aS + lane * 4);
    float4 d4 = *(const float4*)(aD + lane * 4);
    float vs = h.x * s4.x + h.y * s4.y + h.z * s4.z + h.w * s4.w;
    float vd = h.x * d4.x + h.y * d4.y + h.z * d4.z + h.w * d4.w;
#pragma unroll
    for (int off = 1; off <= 4; off <<= 1) {        // reduce 8-lane head groups
        vs += __shfl_xor(vs, off, 64);
        vd += __shfl_xor(vd, off, 64);
    }
    if ((lane & 7) == 0) {
        int head = lane >> 3;
        als[n * 8 + head] = vs;
        ald[n * 8 + head] = vd;
    }
}

__global__ __launch_bounds__(256) void k_att2v(const float* __restrict__ h2,
                                               const float* __restrict__ aS,
                                               const float* __restrict__ aD,
                                               float* __restrict__ als,
                                               float* __restrict__ ald) {
    int n = blockIdx.x * 8 + (threadIdx.x >> 5);   // 32-lane group per node
    int l32 = threadIdx.x & 31;
    if (n >= NN) return;
    float4 h = *(const float4*)(h2 + (size_t)n * 128 + l32 * 4);
    float4 s4 = *(const float4*)(aS + l32 * 4);
    float4 d4 = *(const float4*)(aD + l32 * 4);
    float vs = h.x * s4.x + h.y * s4.y + h.z * s4.z + h.w * s4.w;
    float vd = h.x * d4.x + h.y * d4.y + h.z * d4.z + h.w * d4.w;
#pragma unroll
    for (int off = 1; off <= 16; off <<= 1) {
        vs += __shfl_xor(vs, off, 32);
        vd += __shfl_xor(vd, off, 32);
    }
    if (l32 == 0) { als[n] = vs; ald[n] = vd; }
}

// ---------------------------------------------------------------------------
// Layer 1 aggregation: one block (256 thr) per destination node.
// ---------------------------------------------------------------------------
__global__ __launch_bounds__(256) void k_aggregate1(
    const float* __restrict__ h1, const float* __restrict__ als,
    const float* __restrict__ ald, const int* __restrict__ offsets,
    const int* __restrict__ sorted, const int* __restrict__ ei,
    const float* __restrict__ b1, float* __restrict__ out1) {
    int n = blockIdx.x;
    int tid = threadIdx.x;
    int head = tid >> 5, lane = tid & 31;
    int base = offsets[n];
    int deg = offsets[n + 1] - base;
    __shared__ float m_s[8];
    __shared__ float w_s[32][8];
    __shared__ int s_s[32];

    float aldv = ald[n * 8 + head];
    float mloc = -1e30f;
    for (int i = lane; i < deg; i += 32) {
        int e = sorted[base + i];
        int s = (e < EE) ? ei[e] : (e - EE);
        float v = als[s * 8 + head] + aldv;
        v = (v >= 0.f) ? v : 0.2f * v;
        mloc = fmaxf(mloc, v);
    }
#pragma unroll
    for (int off = 16; off >= 1; off >>= 1)
        mloc = fmaxf(mloc, __shfl_xor(mloc, off, 32));
    if (lane == 0) m_s[head] = mloc;
    __syncthreads();

    int fi = tid >> 3, fh = tid & 7;     // fill roles: 32 edges x 8 heads
    float aldf = ald[n * 8 + fh];
    float mf = m_s[fh];
    float acc = 0.f, dsum = 0.f;
    for (int chunk = 0; chunk < deg; chunk += 32) {
        int len = min(32, deg - chunk);
        if (fi < len) {
            int e = sorted[base + chunk + fi];
            int s = (e < EE) ? ei[e] : (e - EE);
            if (fh == 0) s_s[fi] = s;
            float v = als[s * 8 + fh] + aldf;
            v = (v >= 0.f) ? v : 0.2f * v;
            w_s[fi][fh] = expf(v - mf);
        }
        __syncthreads();
        for (int i = 0; i < len; i++) {
            float w = w_s[i][head];
            int s = s_s[i];
            acc += w * h1[(size_t)s * 256 + tid];
            dsum += w;
        }
        __syncthreads();
    }
    float r = acc / (dsum + 1e-16f) + b1[tid];
    out1[(size_t)n * 256 + tid] = (r >= 0.f) ? r : 0.2f * r;  // module LeakyReLU
}

// ---------------------------------------------------------------------------
// Layer 2 aggregation: one block (128 thr) per destination node, 1 head, C=128
// ---------------------------------------------------------------------------
__global__ __launch_bounds__(128) void k_aggregate2(
    const float* __restrict__ h2, const float* __restrict__ als,
    const float* __restrict__ ald, const int* __restrict__ offsets,
    const int* __restrict__ sorted, const int* __restrict__ ei,
    const float* __restrict__ b2, float* __restrict__ out) {
    int n = blockIdx.x;
    int tid = threadIdx.x;
    int base = offsets[n];
    int deg = offsets[n + 1] - base;
    __shared__ float w_s[128];
    __shared__ int s_s[128];
    __shared__ float red[2];

    float aldv = ald[n];
    float mloc = -1e30f;
    for (int i = tid; i < deg; i += 128) {
        int e = sorted[base + i];
        int s = (e < EE) ? ei[e] : (e - EE);
        float v = als[s] + aldv;
        v = (v >= 0.f) ? v : 0.2f * v;
        mloc = fmaxf(mloc, v);
    }
#pragma unroll
    for (int off = 32; off >= 1; off >>= 1)
        mloc = fmaxf(mloc, __shfl_xor(mloc, off, 64));
    if ((tid & 63) == 0) red[tid >> 6] = mloc;
    __syncthreads();
    float m = fmaxf(red[0], red[1]);

    float acc = 0.f, dsum = 0.f;
    for (int chunk = 0; chunk < deg; chunk += 128) {
        int len = min(128, deg - chunk);
        if (tid < len) {
            int e = sorted[base + chunk + tid];
            int s = (e < EE) ? ei[e] : (e - EE);
            s_s[tid] = s;
            float v = als[s] + aldv;
            v = (v >= 0.f) ? v : 0.2f * v;
            w_s[tid] = expf(v - m);
        }
        __syncthreads();
        for (int i = 0; i < len; i++) {
            float w = w_s[i];
            acc += w * h2[(size_t)s_s[i] * 128 + tid];
            dsum += w;
        }
        __syncthreads();
    }
    out[(size_t)n * 128 + tid] = acc / (dsum + 1e-16f) + b2[tid];
}

// ---------------------------------------------------------------------------
extern "C" void kernel_launch(void* const* d_in, const int* in_sizes, int n_in,
                              void* d_out, int out_size, void* d_ws, size_t ws_size,
                              hipStream_t stream) {
    const int* ei = (const int*)d_in[0];         // [2, EE] int32
    const float* x = (const float*)d_in[1];      // [N, 256]
    const float* W1 = (const float*)d_in[2];     // [256, 256]
    const float* aS1 = (const float*)d_in[3];    // [8, 32]
    const float* aD1 = (const float*)d_in[4];    // [8, 32]
    const float* b1 = (const float*)d_in[5];     // [256]
    const float* W2 = (const float*)d_in[6];     // [128, 256]
    const float* aS2 = (const float*)d_in[7];    // [1, 128]
    const float* aD2 = (const float*)d_in[8];    // [1, 128]
    const float* b2 = (const float*)d_in[9];     // [128]
    float* out = (float*)d_out;

    char* w = (char*)d_ws;
    auto alloc = [&](size_t bytes) {
        char* p = w;
        w += (bytes + 255) & ~(size_t)255;
        return p;
    };
    float* h1   = (float*)alloc((size_t)NN * 256 * 4);   // also reused as h2
    float* out1 = (float*)alloc((size_t)NN * 256 * 4);
    float* als1 = (float*)alloc((size_t)NN * 8 * 4);     // reused as als2
    float* ald1 = (float*)alloc((size_t)NN * 8 * 4);     // reused as ald2
    int* deg     = (int*)alloc((size_t)(NN + 1) * 4);
    int* offsets = (int*)alloc((size_t)(NN + 1) * 4);
    int* cursor  = (int*)alloc((size_t)NN * 4);
    int* sorted  = (int*)alloc((size_t)ET * 4);
    int* bsum    = (int*)alloc(64 * 4);
    float* h2 = h1;
    float* als2 = als1;
    float* ald2 = ald1;

    const int nb = (NN + 1023) / 1024;

    hipMemsetAsync(deg, 0, (size_t)NN * 4, stream);
    hipMemsetAsync(cursor, 0, (size_t)NN * 4, stream);

    // CSR build
    k_hist<<<(ET + 255) / 256, 256, 0, stream>>>(ei, deg);
    k_scan_block<<<nb, 1024, 0, stream>>>(deg, offsets, bsum, NN);
    k_scan_bsums<<<1, 64, 0, stream>>>(bsum, nb);
    k_add_off<<<(NN + 255) / 256, 256, 0, stream>>>(offsets, bsum, NN, ET);
    k_scatter<<<(ET + 255) / 256, 256, 0, stream>>>(ei, offsets, cursor, sorted);

    // Layer 1
    gemm_bf16x3<256><<<(NN + 127) / 128, 512, 0, stream>>>(x, W1, h1, NN);
    k_att1v<<<(NN + 3) / 4, 256, 0, stream>>>(h1, aS1, aD1, als1, ald1);
    k_aggregate1<<<NN, 256, 0, stream>>>(h1, als1, ald1, offsets, sorted, ei, b1, out1);

    // Layer 2
    gemm_bf16x3<128><<<(NN + 127) / 128, 512, 0, stream>>>(out1, W2, h2, NN);
    k_att2v<<<(NN + 7) / 8, 256, 0, stream>>>(h2, aS2, aD2, als2, ald2);
    k_aggregate2<<<NN, 128, 0, stream>>>(h2, als2, ald2, offsets, sorted, ei, b2, out);
}

// Round 3
// 351.769 us; speedup vs baseline: 1.6765x; 1.1779x over previous
//
#include <hip/hip_runtime.h>
#include <hip/hip_bf16.h>
#include <math.h>

// Problem constants (from reference)
#define NN 50000
#define EE 800000
#define ET 850000   // EE + NN self loops
#define NFEATS 256
#define NHIDS 32
#define NHEADS 8
#define NOUT 128

typedef __attribute__((ext_vector_type(8))) short bf16x8;
typedef __attribute__((ext_vector_type(4))) float f32x4;

__device__ inline ushort f2bf(float x) {
    __hip_bfloat16 b = __float2bfloat16(x);   // RTN
    return *reinterpret_cast<ushort*>(&b);
}
__device__ inline float bf2f(ushort u) {
    unsigned v = ((unsigned)u) << 16;
    return __builtin_bit_cast(float, v);
}

// ---------------------------------------------------------------------------
// CSR build: histogram -> scan -> scatter (stores SRC id directly)
// ---------------------------------------------------------------------------
__global__ void k_hist(const int* __restrict__ ei, int* __restrict__ deg) {
    int e = blockIdx.x * blockDim.x + threadIdx.x;
    if (e >= ET) return;
    int d = (e < EE) ? ei[EE + e] : (e - EE);
    atomicAdd(&deg[d], 1);
}

__global__ void k_scan_block(const int* __restrict__ deg, int* __restrict__ offsets,
                             int* __restrict__ bsum, int n) {
    __shared__ int lds[1024];
    int i = blockIdx.x * 1024 + threadIdx.x;
    int v = (i < n) ? deg[i] : 0;
    lds[threadIdx.x] = v;
    __syncthreads();
    for (int off = 1; off < 1024; off <<= 1) {
        int t = 0;
        if ((int)threadIdx.x >= off) t = lds[threadIdx.x - off];
        __syncthreads();
        lds[threadIdx.x] += t;
        __syncthreads();
    }
    if (i < n) offsets[i] = lds[threadIdx.x] - v;   // exclusive within block
    if (threadIdx.x == 1023) bsum[blockIdx.x] = lds[1023];
}

__global__ void k_scan_bsums(int* __restrict__ bsum, int nb) {
    int t = threadIdx.x;                 // single block, 64 threads, nb <= 64
    int v0 = (t < nb) ? bsum[t] : 0;
    int v = v0;
    for (int off = 1; off < 64; off <<= 1) {
        int u = __shfl_up(v, off, 64);
        if (t >= off) v += u;
    }
    if (t < nb) bsum[t] = v - v0;        // exclusive block offsets
}

__global__ void k_add_off(int* __restrict__ offsets, const int* __restrict__ bsum,
                          int n, int total) {
    int i = blockIdx.x * blockDim.x + threadIdx.x;
    if (i < n) offsets[i] += bsum[i >> 10];
    if (i == 0) offsets[n] = total;
}

__global__ void k_scatter(const int* __restrict__ ei, const int* __restrict__ offsets,
                          int* __restrict__ cursor, int* __restrict__ srcs) {
    int e = blockIdx.x * blockDim.x + threadIdx.x;
    if (e >= ET) return;
    int d, s;
    if (e < EE) { d = ei[EE + e]; s = ei[e]; }
    else        { d = e - EE;     s = e - EE; }
    int pos = offsets[d] + atomicAdd(&cursor[d], 1);
    srcs[pos] = s;
}

// ---------------------------------------------------------------------------
// bf16x3 MFMA GEMM: C[m][n] = sum_k A[m][k]*B[n][k], fp32 in, fp32+bf16 out.
// ---------------------------------------------------------------------------
template <int TBN>
__global__ __launch_bounds__(512) void gemm_bf16x3(const float* __restrict__ A,
                                                   const float* __restrict__ Bw,
                                                   float* __restrict__ C,
                                                   ushort* __restrict__ Cb, int M) {
    constexpr int K = 256;
    constexpr int WN = TBN / 4;    // wave n-tile: 64 or 32
    constexpr int NF = WN / 16;    // n-frags per wave: 4 or 2
    __shared__ ushort Ah[128][40], Al[128][40];
    __shared__ ushort Bh[TBN][40], Bl[TBN][40];

    int tid = threadIdx.x;
    int wid = tid >> 6, lane = tid & 63;
    int wm = wid >> 2, wn = wid & 3;          // 2 x 4 wave grid
    int m0 = blockIdx.x * 128;

    f32x4 acc[4][NF];
#pragma unroll
    for (int i = 0; i < 4; i++)
#pragma unroll
        for (int j = 0; j < NF; j++) acc[i][j] = (f32x4){0.f, 0.f, 0.f, 0.f};

    for (int k0 = 0; k0 < K; k0 += 32) {
        // stage A tile: 128 rows x 8 float4 = 1024 slots / 512 thr = 2 each
#pragma unroll
        for (int i = 0; i < 2; i++) {
            int s = tid + 512 * i;
            int r = s >> 3, c4 = s & 7;
            float4 v = make_float4(0.f, 0.f, 0.f, 0.f);
            if (m0 + r < M) v = *(const float4*)(A + (size_t)(m0 + r) * K + k0 + c4 * 4);
            ushort4 hi, lo;
            hi.x = f2bf(v.x); lo.x = f2bf(v.x - bf2f(hi.x));
            hi.y = f2bf(v.y); lo.y = f2bf(v.y - bf2f(hi.y));
            hi.z = f2bf(v.z); lo.z = f2bf(v.z - bf2f(hi.z));
            hi.w = f2bf(v.w); lo.w = f2bf(v.w - bf2f(hi.w));
            *(ushort4*)&Ah[r][c4 * 4] = hi;
            *(ushort4*)&Al[r][c4 * 4] = lo;
        }
        // stage B tile: TBN rows x 8 float4 slots
#pragma unroll
        for (int i = 0; i < TBN / 64; i++) {
            int s = tid + 512 * i;
            int r = s >> 3, c4 = s & 7;
            float4 v = *(const float4*)(Bw + (size_t)r * K + k0 + c4 * 4);
            ushort4 hi, lo;
            hi.x = f2bf(v.x); lo.x = f2bf(v.x - bf2f(hi.x));
            hi.y = f2bf(v.y); lo.y = f2bf(v.y - bf2f(hi.y));
            hi.z = f2bf(v.z); lo.z = f2bf(v.z - bf2f(hi.z));
            hi.w = f2bf(v.w); lo.w = f2bf(v.w - bf2f(hi.w));
            *(ushort4*)&Bh[r][c4 * 4] = hi;
            *(ushort4*)&Bl[r][c4 * 4] = lo;
        }
        __syncthreads();

        int koff = (lane >> 4) * 8;          // k-offset within BK=32
        int rsel = lane & 15;
        bf16x8 ah[4], al[4], bh[NF], bl[NF];
#pragma unroll
        for (int mf = 0; mf < 4; mf++) {
            int r = wm * 64 + mf * 16 + rsel;
            ah[mf] = *(const bf16x8*)&Ah[r][koff];
            al[mf] = *(const bf16x8*)&Al[r][koff];
        }
#pragma unroll
        for (int nf = 0; nf < NF; nf++) {
            int c = wn * WN + nf * 16 + rsel;
            bh[nf] = *(const bf16x8*)&Bh[c][koff];
            bl[nf] = *(const bf16x8*)&Bl[c][koff];
        }
#pragma unroll
        for (int mf = 0; mf < 4; mf++)
#pragma unroll
            for (int nf = 0; nf < NF; nf++) {
                acc[mf][nf] = __builtin_amdgcn_mfma_f32_16x16x32_bf16(ah[mf], bh[nf], acc[mf][nf], 0, 0, 0);
                acc[mf][nf] = __builtin_amdgcn_mfma_f32_16x16x32_bf16(ah[mf], bl[nf], acc[mf][nf], 0, 0, 0);
                acc[mf][nf] = __builtin_amdgcn_mfma_f32_16x16x32_bf16(al[mf], bh[nf], acc[mf][nf], 0, 0, 0);
            }
        __syncthreads();
    }

    // epilogue: C/D layout col = lane&15, row = (lane>>4)*4 + j
#pragma unroll
    for (int mf = 0; mf < 4; mf++) {
        int gr = m0 + wm * 64 + mf * 16 + (lane >> 4) * 4;
#pragma unroll
        for (int nf = 0; nf < NF; nf++) {
            int gc = wn * WN + nf * 16 + (lane & 15);
#pragma unroll
            for (int j = 0; j < 4; j++) {
                if (gr + j < M) {
                    float v = acc[mf][nf][j];
                    C[(size_t)(gr + j) * TBN + gc] = v;
                    Cb[(size_t)(gr + j) * TBN + gc] = f2bf(v);
                }
            }
        }
    }
}

// ---------------------------------------------------------------------------
// attention logits (vectorized: float4 per lane, fp32 h)
// ---------------------------------------------------------------------------
__global__ __launch_bounds__(256) void k_att1v(const float* __restrict__ h1,
                                               const float* __restrict__ aS,
                                               const float* __restrict__ aD,
                                               float* __restrict__ als,
                                               float* __restrict__ ald) {
    int n = blockIdx.x * 4 + (threadIdx.x >> 6);   // wave per node
    int lane = threadIdx.x & 63;
    if (n >= NN) return;
    float4 h = *(const float4*)(h1 + (size_t)n * 256 + lane * 4);
    float4 s4 = *(const float4*)(aS + lane * 4);
    float4 d4 = *(const float4*)(aD + lane * 4);
    float vs = h.x * s4.x + h.y * s4.y + h.z * s4.z + h.w * s4.w;
    float vd = h.x * d4.x + h.y * d4.y + h.z * d4.z + h.w * d4.w;
#pragma unroll
    for (int off = 1; off <= 4; off <<= 1) {        // reduce 8-lane head groups
        vs += __shfl_xor(vs, off, 64);
        vd += __shfl_xor(vd, off, 64);
    }
    if ((lane & 7) == 0) {
        int head = lane >> 3;
        als[n * 8 + head] = vs;
        ald[n * 8 + head] = vd;
    }
}

__global__ __launch_bounds__(256) void k_att2v(const float* __restrict__ h2,
                                               const float* __restrict__ aS,
                                               const float* __restrict__ aD,
                                               float* __restrict__ als,
                                               float* __restrict__ ald) {
    int n = blockIdx.x * 8 + (threadIdx.x >> 5);   // 32-lane group per node
    int l32 = threadIdx.x & 31;
    if (n >= NN) return;
    float4 h = *(const float4*)(h2 + (size_t)n * 128 + l32 * 4);
    float4 s4 = *(const float4*)(aS + l32 * 4);
    float4 d4 = *(const float4*)(aD + l32 * 4);
    float vs = h.x * s4.x + h.y * s4.y + h.z * s4.z + h.w * s4.w;
    float vd = h.x * d4.x + h.y * d4.y + h.z * d4.z + h.w * d4.w;
#pragma unroll
    for (int off = 1; off <= 16; off <<= 1) {
        vs += __shfl_xor(vs, off, 32);
        vd += __shfl_xor(vd, off, 32);
    }
    if (l32 == 0) { als[n] = vs; ald[n] = vd; }
}

// ---------------------------------------------------------------------------
// Layer 1 aggregation: 128 thr (2 independent waves) per dst node; bf16 gather,
// no segment-max (logits <= ~5, exp safe; alpha mathematically identical),
// shuffle-broadcast weights (no LDS, no barriers).
// Thread owns comps (2*tid, 2*tid+1); head = tid>>4.
// ---------------------------------------------------------------------------
__global__ __launch_bounds__(128) void k_agg1(
    const ushort* __restrict__ h1b, const float* __restrict__ als,
    const float* __restrict__ ald, const int* __restrict__ offsets,
    const int* __restrict__ srcs, const float* __restrict__ b1,
    float* __restrict__ out1) {
    int n = blockIdx.x;
    int tid = threadIdx.x;            // 0..127
    int lane = tid & 63;
    int wv = tid >> 6;                // wave id 0/1
    int hl = lane >> 4;               // local head 0..3 (global head = wv*4+hl)
    int base = offsets[n], deg = offsets[n + 1] - base;

    // stage roles: edge eL = lane>>2 (0..15), head hS = wv*4 + (lane&3)
    int eL = lane >> 2;
    int hS = wv * 4 + (lane & 3);
    float aldS = ald[n * 8 + hS];

    float acc0 = 0.f, acc1 = 0.f, dsum = 0.f;
    for (int chunk = 0; chunk < deg; chunk += 16) {
        int len = min(16, deg - chunk);
        int idx = chunk + eL; if (idx >= deg) idx = deg - 1;
        int sE = srcs[base + idx];
        float v = als[sE * 8 + hS] + aldS;
        v = (v >= 0.f) ? v : 0.2f * v;
        float wE = __expf(v);
        for (int i = 0; i < len; i++) {
            int si = __shfl(sE, i * 4, 64);
            float wi = __shfl(wE, i * 4 + hl, 64);
            unsigned u = *(const unsigned*)(h1b + (size_t)si * 256 + 2 * tid);
            acc0 += wi * __builtin_bit_cast(float, u << 16);
            acc1 += wi * __builtin_bit_cast(float, u & 0xffff0000u);
            dsum += wi;
        }
    }
    float inv = 1.f / (dsum + 1e-16f);
    float r0 = acc0 * inv + b1[2 * tid];
    float r1 = acc1 * inv + b1[2 * tid + 1];
    r0 = (r0 >= 0.f) ? r0 : 0.2f * r0;   // module LeakyReLU
    r1 = (r1 >= 0.f) ? r1 : 0.2f * r1;
    *(float2*)(out1 + (size_t)n * 256 + 2 * tid) = make_float2(r0, r1);
}

// ---------------------------------------------------------------------------
// Layer 2 aggregation: 1 wave per dst node, 1 head, C=128; bf16 gather.
// ---------------------------------------------------------------------------
__global__ __launch_bounds__(64) void k_agg2(
    const ushort* __restrict__ h2b, const float* __restrict__ als,
    const float* __restrict__ ald, const int* __restrict__ offsets,
    const int* __restrict__ srcs, const float* __restrict__ b2,
    float* __restrict__ out) {
    int n = blockIdx.x;
    int lane = threadIdx.x;           // 0..63, owns comps 2*lane, 2*lane+1
    int base = offsets[n], deg = offsets[n + 1] - base;
    float aldv = ald[n];

    float acc0 = 0.f, acc1 = 0.f, dsum = 0.f;
    for (int chunk = 0; chunk < deg; chunk += 64) {
        int len = min(64, deg - chunk);
        int idx = chunk + lane; if (idx >= deg) idx = deg - 1;
        int sE = srcs[base + idx];
        float v = als[sE] + aldv;
        v = (v >= 0.f) ? v : 0.2f * v;
        float wE = __expf(v);
        for (int i = 0; i < len; i++) {
            int si = __shfl(sE, i, 64);
            float wi = __shfl(wE, i, 64);
            unsigned u = *(const unsigned*)(h2b + (size_t)si * 128 + 2 * lane);
            acc0 += wi * __builtin_bit_cast(float, u << 16);
            acc1 += wi * __builtin_bit_cast(float, u & 0xffff0000u);
            dsum += wi;
        }
    }
    float inv = 1.f / (dsum + 1e-16f);
    *(float2*)(out + (size_t)n * 128 + 2 * lane) =
        make_float2(acc0 * inv + b2[2 * lane], acc1 * inv + b2[2 * lane + 1]);
}

// ---------------------------------------------------------------------------
extern "C" void kernel_launch(void* const* d_in, const int* in_sizes, int n_in,
                              void* d_out, int out_size, void* d_ws, size_t ws_size,
                              hipStream_t stream) {
    const int* ei = (const int*)d_in[0];         // [2, EE] int32
    const float* x = (const float*)d_in[1];      // [N, 256]
    const float* W1 = (const float*)d_in[2];     // [256, 256]
    const float* aS1 = (const float*)d_in[3];    // [8, 32]
    const float* aD1 = (const float*)d_in[4];    // [8, 32]
    const float* b1 = (const float*)d_in[5];     // [256]
    const float* W2 = (const float*)d_in[6];     // [128, 256]
    const float* aS2 = (const float*)d_in[7];    // [1, 128]
    const float* aD2 = (const float*)d_in[8];    // [1, 128]
    const float* b2 = (const float*)d_in[9];     // [128]
    float* out = (float*)d_out;

    char* w = (char*)d_ws;
    auto alloc = [&](size_t bytes) {
        char* p = w;
        w += (bytes + 255) & ~(size_t)255;
        return p;
    };
    float*  h1f  = (float*)alloc((size_t)NN * 256 * 4);   // reused as h2f
    ushort* h1b  = (ushort*)alloc((size_t)NN * 256 * 2);  // reused as h2b
    float*  out1 = (float*)alloc((size_t)NN * 256 * 4);
    float*  als1 = (float*)alloc((size_t)NN * 8 * 4);     // reused as als2
    float*  ald1 = (float*)alloc((size_t)NN * 8 * 4);     // reused as ald2
    int* deg     = (int*)alloc((size_t)(NN + 1) * 4);
    int* offsets = (int*)alloc((size_t)(NN + 1) * 4);
    int* cursor  = (int*)alloc((size_t)NN * 4);
    int* srcs    = (int*)alloc((size_t)ET * 4);
    int* bsum    = (int*)alloc(64 * 4);
    float*  h2f = h1f;
    ushort* h2b = h1b;
    float* als2 = als1;
    float* ald2 = ald1;

    const int nb = (NN + 1023) / 1024;

    hipMemsetAsync(deg, 0, (size_t)NN * 4, stream);
    hipMemsetAsync(cursor, 0, (size_t)NN * 4, stream);

    // CSR build
    k_hist<<<(ET + 255) / 256, 256, 0, stream>>>(ei, deg);
    k_scan_block<<<nb, 1024, 0, stream>>>(deg, offsets, bsum, NN);
    k_scan_bsums<<<1, 64, 0, stream>>>(bsum, nb);
    k_add_off<<<(NN + 255) / 256, 256, 0, stream>>>(offsets, bsum, NN, ET);
    k_scatter<<<(ET + 255) / 256, 256, 0, stream>>>(ei, offsets, cursor, srcs);

    // Layer 1
    gemm_bf16x3<256><<<(NN + 127) / 128, 512, 0, stream>>>(x, W1, h1f, h1b, NN);
    k_att1v<<<(NN + 3) / 4, 256, 0, stream>>>(h1f, aS1, aD1, als1, ald1);
    k_agg1<<<NN, 128, 0, stream>>>(h1b, als1, ald1, offsets, srcs, b1, out1);

    // Layer 2
    gemm_bf16x3<128><<<(NN + 127) / 128, 512, 0, stream>>>(out1, W2, h2f, h2b, NN);
    k_att2v<<<(NN + 7) / 8, 256, 0, stream>>>(h2f, aS2, aD2, als2, ald2);
    k_agg2<<<NN, 64, 0, stream>>>(h2b, als2, ald2, offsets, srcs, b2, out);
}

// Round 5
// 303.581 us; speedup vs baseline: 1.9426x; 1.1587x over previous
//
#include <hip/hip_runtime.h>
#include <hip/hip_bf16.h>
#include <math.h>

// Problem constants (from reference)
#define NN 50000
#define EE 800000
#define ET 850000   // EE + NN self loops
#define NFEATS 256
#define NHIDS 32
#define NHEADS 8
#define NOUT 128

typedef __attribute__((ext_vector_type(8))) short bf16x8;
typedef __attribute__((ext_vector_type(4))) float f32x4;

__device__ inline ushort f2bf(float x) {
    __hip_bfloat16 b = __float2bfloat16(x);   // RTN
    return *reinterpret_cast<ushort*>(&b);
}
__device__ inline float bf2f(ushort u) {
    unsigned v = ((unsigned)u) << 16;
    return __builtin_bit_cast(float, v);
}
__device__ inline float bflo(unsigned u) {
    return __builtin_bit_cast(float, u << 16);
}
__device__ inline float bfhi(unsigned u) {
    return __builtin_bit_cast(float, u & 0xffff0000u);
}

// ---------------------------------------------------------------------------
// CSR build: histogram -> scan -> scatter (stores SRC id directly)
// ---------------------------------------------------------------------------
__global__ void k_hist(const int* __restrict__ ei, int* __restrict__ deg) {
    int e = blockIdx.x * blockDim.x + threadIdx.x;
    if (e >= ET) return;
    int d = (e < EE) ? ei[EE + e] : (e - EE);
    atomicAdd(&deg[d], 1);
}

__global__ void k_scan_block(const int* __restrict__ deg, int* __restrict__ offsets,
                             int* __restrict__ bsum, int n) {
    __shared__ int lds[1024];
    int i = blockIdx.x * 1024 + threadIdx.x;
    int v = (i < n) ? deg[i] : 0;
    lds[threadIdx.x] = v;
    __syncthreads();
    for (int off = 1; off < 1024; off <<= 1) {
        int t = 0;
        if ((int)threadIdx.x >= off) t = lds[threadIdx.x - off];
        __syncthreads();
        lds[threadIdx.x] += t;
        __syncthreads();
    }
    if (i < n) offsets[i] = lds[threadIdx.x] - v;   // exclusive within block
    if (threadIdx.x == 1023) bsum[blockIdx.x] = lds[1023];
}

__global__ void k_scan_bsums(int* __restrict__ bsum, int nb) {
    int t = threadIdx.x;                 // single block, 64 threads, nb <= 64
    int v0 = (t < nb) ? bsum[t] : 0;
    int v = v0;
    for (int off = 1; off < 64; off <<= 1) {
        int u = __shfl_up(v, off, 64);
        if (t >= off) v += u;
    }
    if (t < nb) bsum[t] = v - v0;        // exclusive block offsets
}

__global__ void k_add_off(int* __restrict__ offsets, const int* __restrict__ bsum,
                          int n, int total) {
    int i = blockIdx.x * blockDim.x + threadIdx.x;
    if (i < n) offsets[i] += bsum[i >> 10];
    if (i == 0) offsets[n] = total;
}

__global__ void k_scatter(const int* __restrict__ ei, const int* __restrict__ offsets,
                          int* __restrict__ cursor, int* __restrict__ srcs) {
    int e = blockIdx.x * blockDim.x + threadIdx.x;
    if (e >= ET) return;
    int d, s;
    if (e < EE) { d = ei[EE + e]; s = ei[e]; }
    else        { d = e - EE;     s = e - EE; }
    int pos = offsets[d] + atomicAdd(&cursor[d], 1);
    srcs[pos] = s;
}

// ---------------------------------------------------------------------------
// bf16x3 MFMA GEMM: C[m][n] = sum_k A[m][k]*B[n][k], fp32 in, fp32+bf16 out.
// ---------------------------------------------------------------------------
template <int TBN>
__global__ __launch_bounds__(512) void gemm_bf16x3(const float* __restrict__ A,
                                                   const float* __restrict__ Bw,
                                                   float* __restrict__ C,
                                                   ushort* __restrict__ Cb, int M) {
    constexpr int K = 256;
    constexpr int WN = TBN / 4;    // wave n-tile: 64 or 32
    constexpr int NF = WN / 16;    // n-frags per wave: 4 or 2
    __shared__ ushort Ah[128][40], Al[128][40];
    __shared__ ushort Bh[TBN][40], Bl[TBN][40];

    int tid = threadIdx.x;
    int wid = tid >> 6, lane = tid & 63;
    int wm = wid >> 2, wn = wid & 3;          // 2 x 4 wave grid
    int m0 = blockIdx.x * 128;

    f32x4 acc[4][NF];
#pragma unroll
    for (int i = 0; i < 4; i++)
#pragma unroll
        for (int j = 0; j < NF; j++) acc[i][j] = (f32x4){0.f, 0.f, 0.f, 0.f};

    for (int k0 = 0; k0 < K; k0 += 32) {
        // stage A tile: 128 rows x 8 float4 = 1024 slots / 512 thr = 2 each
#pragma unroll
        for (int i = 0; i < 2; i++) {
            int s = tid + 512 * i;
            int r = s >> 3, c4 = s & 7;
            float4 v = make_float4(0.f, 0.f, 0.f, 0.f);
            if (m0 + r < M) v = *(const float4*)(A + (size_t)(m0 + r) * K + k0 + c4 * 4);
            ushort4 hi, lo;
            hi.x = f2bf(v.x); lo.x = f2bf(v.x - bf2f(hi.x));
            hi.y = f2bf(v.y); lo.y = f2bf(v.y - bf2f(hi.y));
            hi.z = f2bf(v.z); lo.z = f2bf(v.z - bf2f(hi.z));
            hi.w = f2bf(v.w); lo.w = f2bf(v.w - bf2f(hi.w));
            *(ushort4*)&Ah[r][c4 * 4] = hi;
            *(ushort4*)&Al[r][c4 * 4] = lo;
        }
        // stage B tile: TBN rows x 8 float4 slots
#pragma unroll
        for (int i = 0; i < TBN / 64; i++) {
            int s = tid + 512 * i;
            int r = s >> 3, c4 = s & 7;
            float4 v = *(const float4*)(Bw + (size_t)r * K + k0 + c4 * 4);
            ushort4 hi, lo;
            hi.x = f2bf(v.x); lo.x = f2bf(v.x - bf2f(hi.x));
            hi.y = f2bf(v.y); lo.y = f2bf(v.y - bf2f(hi.y));
            hi.z = f2bf(v.z); lo.z = f2bf(v.z - bf2f(hi.z));
            hi.w = f2bf(v.w); lo.w = f2bf(v.w - bf2f(hi.w));
            *(ushort4*)&Bh[r][c4 * 4] = hi;
            *(ushort4*)&Bl[r][c4 * 4] = lo;
        }
        __syncthreads();

        int koff = (lane >> 4) * 8;          // k-offset within BK=32
        int rsel = lane & 15;
        bf16x8 ah[4], al[4], bh[NF], bl[NF];
#pragma unroll
        for (int mf = 0; mf < 4; mf++) {
            int r = wm * 64 + mf * 16 + rsel;
            ah[mf] = *(const bf16x8*)&Ah[r][koff];
            al[mf] = *(const bf16x8*)&Al[r][koff];
        }
#pragma unroll
        for (int nf = 0; nf < NF; nf++) {
            int c = wn * WN + nf * 16 + rsel;
            bh[nf] = *(const bf16x8*)&Bh[c][koff];
            bl[nf] = *(const bf16x8*)&Bl[c][koff];
        }
#pragma unroll
        for (int mf = 0; mf < 4; mf++)
#pragma unroll
            for (int nf = 0; nf < NF; nf++) {
                acc[mf][nf] = __builtin_amdgcn_mfma_f32_16x16x32_bf16(ah[mf], bh[nf], acc[mf][nf], 0, 0, 0);
                acc[mf][nf] = __builtin_amdgcn_mfma_f32_16x16x32_bf16(ah[mf], bl[nf], acc[mf][nf], 0, 0, 0);
                acc[mf][nf] = __builtin_amdgcn_mfma_f32_16x16x32_bf16(al[mf], bh[nf], acc[mf][nf], 0, 0, 0);
            }
        __syncthreads();
    }

    // epilogue: C/D layout col = lane&15, row = (lane>>4)*4 + j
#pragma unroll
    for (int mf = 0; mf < 4; mf++) {
        int gr = m0 + wm * 64 + mf * 16 + (lane >> 4) * 4;
#pragma unroll
        for (int nf = 0; nf < NF; nf++) {
            int gc = wn * WN + nf * 16 + (lane & 15);
#pragma unroll
            for (int j = 0; j < 4; j++) {
                if (gr + j < M) {
                    float v = acc[mf][nf][j];
                    C[(size_t)(gr + j) * TBN + gc] = v;
                    Cb[(size_t)(gr + j) * TBN + gc] = f2bf(v);
                }
            }
        }
    }
}

// ---------------------------------------------------------------------------
// attention logits (vectorized: float4 per lane, fp32 h)
// ---------------------------------------------------------------------------
__global__ __launch_bounds__(256) void k_att1v(const float* __restrict__ h1,
                                               const float* __restrict__ aS,
                                               const float* __restrict__ aD,
                                               float* __restrict__ als,
                                               float* __restrict__ ald) {
    int n = blockIdx.x * 4 + (threadIdx.x >> 6);   // wave per node
    int lane = threadIdx.x & 63;
    if (n >= NN) return;
    float4 h = *(const float4*)(h1 + (size_t)n * 256 + lane * 4);
    float4 s4 = *(const float4*)(aS + lane * 4);
    float4 d4 = *(const float4*)(aD + lane * 4);
    float vs = h.x * s4.x + h.y * s4.y + h.z * s4.z + h.w * s4.w;
    float vd = h.x * d4.x + h.y * d4.y + h.z * d4.z + h.w * d4.w;
#pragma unroll
    for (int off = 1; off <= 4; off <<= 1) {        // reduce 8-lane head groups
        vs += __shfl_xor(vs, off, 64);
        vd += __shfl_xor(vd, off, 64);
    }
    if ((lane & 7) == 0) {
        int head = lane >> 3;
        als[n * 8 + head] = vs;
        ald[n * 8 + head] = vd;
    }
}

__global__ __launch_bounds__(256) void k_att2v(const float* __restrict__ h2,
                                               const float* __restrict__ aS,
                                               const float* __restrict__ aD,
                                               float* __restrict__ als,
                                               float* __restrict__ ald) {
    int n = blockIdx.x * 8 + (threadIdx.x >> 5);   // 32-lane group per node
    int l32 = threadIdx.x & 31;
    if (n >= NN) return;
    float4 h = *(const float4*)(h2 + (size_t)n * 128 + l32 * 4);
    float4 s4 = *(const float4*)(aS + l32 * 4);
    float4 d4 = *(const float4*)(aD + l32 * 4);
    float vs = h.x * s4.x + h.y * s4.y + h.z * s4.z + h.w * s4.w;
    float vd = h.x * d4.x + h.y * d4.y + h.z * d4.z + h.w * d4.w;
#pragma unroll
    for (int off = 1; off <= 16; off <<= 1) {
        vs += __shfl_xor(vs, off, 32);
        vd += __shfl_xor(vd, off, 32);
    }
    if (l32 == 0) { als[n] = vs; ald[n] = vd; }
}

// ---------------------------------------------------------------------------
// Layer 1 aggregation: round-3-verified mapping (128 thr, 2 waves; wave wv
// handles heads wv*4..wv*4+3; thread owns comps 2*tid, 2*tid+1).
// Loop restructured: full 16-edge chunks use a compile-time-unrolled,
// fully wave-uniform body (16 independent gathers in flight); tail is
// round 3's exact runtime loop.
// ---------------------------------------------------------------------------
__global__ __launch_bounds__(128) void k_agg1(
    const ushort* __restrict__ h1b, const float* __restrict__ als,
    const float* __restrict__ ald, const int* __restrict__ offsets,
    const int* __restrict__ srcs, const float* __restrict__ b1,
    float* __restrict__ out1) {
    int n = blockIdx.x;
    int tid = threadIdx.x;            // 0..127
    int lane = tid & 63;
    int wv = tid >> 6;                // wave id 0/1
    int hl = lane >> 4;               // local head 0..3 (global head = wv*4+hl)
    int base = offsets[n], deg = offsets[n + 1] - base;

    // stage roles: edge eL = lane>>2 (0..15), head hS = wv*4 + (lane&3)
    int eL = lane >> 2;
    int hS = wv * 4 + (lane & 3);
    float aldS = ald[n * 8 + hS];

    float acc0 = 0.f, acc1 = 0.f, dsum = 0.f;
    int chunk = 0;
    for (; chunk + 16 <= deg; chunk += 16) {        // full chunks: uniform, unrolled
        int sE = srcs[base + chunk + eL];
        float v = als[sE * 8 + hS] + aldS;
        v = (v >= 0.f) ? v : 0.2f * v;
        float wE = __expf(v);
#pragma unroll
        for (int i = 0; i < 16; i++) {
            int si = __shfl(sE, i * 4, 64);
            float wi = __shfl(wE, i * 4 + hl, 64);
            unsigned u = *(const unsigned*)(h1b + (size_t)si * 256 + 2 * tid);
            acc0 += wi * bflo(u);
            acc1 += wi * bfhi(u);
            dsum += wi;
        }
    }
    if (chunk < deg) {                               // tail: round 3's exact body
        int len = deg - chunk;                       // 1..15, wave-uniform
        int idx = chunk + eL; if (idx >= deg) idx = deg - 1;
        int sE = srcs[base + idx];
        float v = als[sE * 8 + hS] + aldS;
        v = (v >= 0.f) ? v : 0.2f * v;
        float wE = __expf(v);
        for (int i = 0; i < len; i++) {
            int si = __shfl(sE, i * 4, 64);
            float wi = __shfl(wE, i * 4 + hl, 64);
            unsigned u = *(const unsigned*)(h1b + (size_t)si * 256 + 2 * tid);
            acc0 += wi * bflo(u);
            acc1 += wi * bfhi(u);
            dsum += wi;
        }
    }
    float inv = 1.f / (dsum + 1e-16f);
    float r0 = acc0 * inv + b1[2 * tid];
    float r1 = acc1 * inv + b1[2 * tid + 1];
    r0 = (r0 >= 0.f) ? r0 : 0.2f * r0;   // module LeakyReLU
    r1 = (r1 >= 0.f) ? r1 : 0.2f * r1;
    *(float2*)(out1 + (size_t)n * 256 + 2 * tid) = make_float2(r0, r1);
}

// ---------------------------------------------------------------------------
// Layer 2 aggregation: round-3-verified mapping (1 wave, thread owns comps
// 2*lane, 2*lane+1). Chunk reduced 64 -> 16 (staged via lane&15) so the
// mean-degree node takes the unrolled full-chunk path; tail = round 3 loop.
// ---------------------------------------------------------------------------
__global__ __launch_bounds__(64) void k_agg2(
    const ushort* __restrict__ h2b, const float* __restrict__ als,
    const float* __restrict__ ald, const int* __restrict__ offsets,
    const int* __restrict__ srcs, const float* __restrict__ b2,
    float* __restrict__ out) {
    int n = blockIdx.x;
    int lane = threadIdx.x;           // 0..63
    int l16 = lane & 15;              // staged edge slot
    int base = offsets[n], deg = offsets[n + 1] - base;
    float aldv = ald[n];

    float acc0 = 0.f, acc1 = 0.f, dsum = 0.f;
    int chunk = 0;
    for (; chunk + 16 <= deg; chunk += 16) {        // full chunks: uniform, unrolled
        int sE = srcs[base + chunk + l16];
        float v = als[sE] + aldv;
        v = (v >= 0.f) ? v : 0.2f * v;
        float wE = __expf(v);
#pragma unroll
        for (int i = 0; i < 16; i++) {
            int si = __shfl(sE, i, 64);
            float wi = __shfl(wE, i, 64);
            unsigned u = *(const unsigned*)(h2b + (size_t)si * 128 + 2 * lane);
            acc0 += wi * bflo(u);
            acc1 += wi * bfhi(u);
            dsum += wi;
        }
    }
    if (chunk < deg) {                               // tail
        int len = deg - chunk;                       // 1..15, wave-uniform
        int idx = chunk + l16; if (idx >= deg) idx = deg - 1;
        int sE = srcs[base + idx];
        float v = als[sE] + aldv;
        v = (v >= 0.f) ? v : 0.2f * v;
        float wE = __expf(v);
        for (int i = 0; i < len; i++) {
            int si = __shfl(sE, i, 64);
            float wi = __shfl(wE, i, 64);
            unsigned u = *(const unsigned*)(h2b + (size_t)si * 128 + 2 * lane);
            acc0 += wi * bflo(u);
            acc1 += wi * bfhi(u);
            dsum += wi;
        }
    }
    float inv = 1.f / (dsum + 1e-16f);
    *(float2*)(out + (size_t)n * 128 + 2 * lane) =
        make_float2(acc0 * inv + b2[2 * lane], acc1 * inv + b2[2 * lane + 1]);
}

// ---------------------------------------------------------------------------
extern "C" void kernel_launch(void* const* d_in, const int* in_sizes, int n_in,
                              void* d_out, int out_size, void* d_ws, size_t ws_size,
                              hipStream_t stream) {
    const int* ei = (const int*)d_in[0];         // [2, EE] int32
    const float* x = (const float*)d_in[1];      // [N, 256]
    const float* W1 = (const float*)d_in[2];     // [256, 256]
    const float* aS1 = (const float*)d_in[3];    // [8, 32]
    const float* aD1 = (const float*)d_in[4];    // [8, 32]
    const float* b1 = (const float*)d_in[5];     // [256]
    const float* W2 = (const float*)d_in[6];     // [128, 256]
    const float* aS2 = (const float*)d_in[7];    // [1, 128]
    const float* aD2 = (const float*)d_in[8];    // [1, 128]
    const float* b2 = (const float*)d_in[9];     // [128]
    float* out = (float*)d_out;

    char* w = (char*)d_ws;
    auto alloc = [&](size_t bytes) {
        char* p = w;
        w += (bytes + 255) & ~(size_t)255;
        return p;
    };
    float*  h1f  = (float*)alloc((size_t)NN * 256 * 4);   // reused as h2f
    ushort* h1b  = (ushort*)alloc((size_t)NN * 256 * 2);  // reused as h2b
    float*  out1 = (float*)alloc((size_t)NN * 256 * 4);
    float*  als1 = (float*)alloc((size_t)NN * 8 * 4);     // reused as als2
    float*  ald1 = (float*)alloc((size_t)NN * 8 * 4);     // reused as ald2
    int* deg     = (int*)alloc((size_t)(NN + 1) * 4);
    int* offsets = (int*)alloc((size_t)(NN + 1) * 4);
    int* cursor  = (int*)alloc((size_t)NN * 4);
    int* srcs    = (int*)alloc((size_t)ET * 4);
    int* bsum    = (int*)alloc(64 * 4);
    float*  h2f = h1f;
    ushort* h2b = h1b;
    float* als2 = als1;
    float* ald2 = ald1;

    const int nb = (NN + 1023) / 1024;

    hipMemsetAsync(deg, 0, (size_t)NN * 4, stream);
    hipMemsetAsync(cursor, 0, (size_t)NN * 4, stream);

    // CSR build
    k_hist<<<(ET + 255) / 256, 256, 0, stream>>>(ei, deg);
    k_scan_block<<<nb, 1024, 0, stream>>>(deg, offsets, bsum, NN);
    k_scan_bsums<<<1, 64, 0, stream>>>(bsum, nb);
    k_add_off<<<(NN + 255) / 256, 256, 0, stream>>>(offsets, bsum, NN, ET);
    k_scatter<<<(ET + 255) / 256, 256, 0, stream>>>(ei, offsets, cursor, srcs);

    // Layer 1
    gemm_bf16x3<256><<<(NN + 127) / 128, 512, 0, stream>>>(x, W1, h1f, h1b, NN);
    k_att1v<<<(NN + 3) / 4, 256, 0, stream>>>(h1f, aS1, aD1, als1, ald1);
    k_agg1<<<NN, 128, 0, stream>>>(h1b, als1, ald1, offsets, srcs, b1, out1);

    // Layer 2
    gemm_bf16x3<128><<<(NN + 127) / 128, 512, 0, stream>>>(out1, W2, h2f, h2b, NN);
    k_att2v<<<(NN + 7) / 8, 256, 0, stream>>>(h2f, aS2, aD2, als2, ald2);
    k_agg2<<<NN, 64, 0, stream>>>(h2b, als2, ald2, offsets, srcs, b2, out);
}

// Round 7
// 294.209 us; speedup vs baseline: 2.0045x; 1.0319x over previous
//
#include <hip/hip_runtime.h>
#include <hip/hip_bf16.h>
#include <math.h>

// Problem constants (from reference)
#define NN 50000
#define EE 800000
#define ET 850000   // EE + NN self loops
#define NFEATS 256
#define NHIDS 32
#define NHEADS 8
#define NOUT 128

typedef __attribute__((ext_vector_type(8))) short bf16x8;
typedef __attribute__((ext_vector_type(4))) float f32x4;
typedef __attribute__((ext_vector_type(8))) unsigned short ushort8_t;

__device__ inline ushort f2bf(float x) {
    __hip_bfloat16 b = __float2bfloat16(x);   // RTN
    return *reinterpret_cast<ushort*>(&b);
}
__device__ inline float bf2f(ushort u) {
    unsigned v = ((unsigned)u) << 16;
    return __builtin_bit_cast(float, v);
}
__device__ inline float bflo(unsigned u) {
    return __builtin_bit_cast(float, u << 16);
}
__device__ inline float bfhi(unsigned u) {
    return __builtin_bit_cast(float, u & 0xffff0000u);
}

// ---------------------------------------------------------------------------
// CSR build: histogram -> scan -> scatter (stores SRC id directly)
// ---------------------------------------------------------------------------
__global__ void k_hist(const int* __restrict__ ei, int* __restrict__ deg) {
    int e = blockIdx.x * blockDim.x + threadIdx.x;
    if (e >= ET) return;
    int d = (e < EE) ? ei[EE + e] : (e - EE);
    atomicAdd(&deg[d], 1);
}

__global__ void k_scan_block(const int* __restrict__ deg, int* __restrict__ offsets,
                             int* __restrict__ bsum, int n) {
    __shared__ int lds[1024];
    int i = blockIdx.x * 1024 + threadIdx.x;
    int v = (i < n) ? deg[i] : 0;
    lds[threadIdx.x] = v;
    __syncthreads();
    for (int off = 1; off < 1024; off <<= 1) {
        int t = 0;
        if ((int)threadIdx.x >= off) t = lds[threadIdx.x - off];
        __syncthreads();
        lds[threadIdx.x] += t;
        __syncthreads();
    }
    if (i < n) offsets[i] = lds[threadIdx.x] - v;   // exclusive within block
    if (threadIdx.x == 1023) bsum[blockIdx.x] = lds[1023];
}

__global__ void k_scan_bsums(int* __restrict__ bsum, int nb) {
    int t = threadIdx.x;                 // single block, 64 threads, nb <= 64
    int v0 = (t < nb) ? bsum[t] : 0;
    int v = v0;
    for (int off = 1; off < 64; off <<= 1) {
        int u = __shfl_up(v, off, 64);
        if (t >= off) v += u;
    }
    if (t < nb) bsum[t] = v - v0;        // exclusive block offsets
}

__global__ void k_add_off(int* __restrict__ offsets, const int* __restrict__ bsum,
                          int n, int total) {
    int i = blockIdx.x * blockDim.x + threadIdx.x;
    if (i < n) offsets[i] += bsum[i >> 10];
    if (i == 0) offsets[n] = total;
}

__global__ void k_scatter(const int* __restrict__ ei, const int* __restrict__ offsets,
                          int* __restrict__ cursor, int* __restrict__ srcs) {
    int e = blockIdx.x * blockDim.x + threadIdx.x;
    if (e >= ET) return;
    int d, s;
    if (e < EE) { d = ei[EE + e]; s = ei[e]; }
    else        { d = e - EE;     s = e - EE; }
    int pos = offsets[d] + atomicAdd(&cursor[d], 1);
    srcs[pos] = s;
}

// ---------------------------------------------------------------------------
// Weight pre-split: fp32 -> (hi, lo) bf16 planes, done once per call.
// ---------------------------------------------------------------------------
__global__ void k_splitW(const float* __restrict__ W, ushort* __restrict__ Wh,
                         ushort* __restrict__ Wl, int n) {
    int i = blockIdx.x * blockDim.x + threadIdx.x;
    if (i >= n) return;
    float v = W[i];
    ushort h = f2bf(v);
    Wh[i] = h;
    Wl[i] = f2bf(v - bf2f(h));
}

// ---------------------------------------------------------------------------
// bf16x3 MFMA GEMM with fused attention-logit epilogue.
// C[m][n] = sum_k A[m][k]*B[n][k]; A fp32, B pre-split bf16 hi/lo.
// Outputs: Cb (bf16 h matrix, gathered by aggregation) and als/ald logits.
// B-staging: each slot copies 16 ushorts (2 aligned ushort8 writes) so the
// full 32-col K-tile is covered (bug fixed from round 6).
// ---------------------------------------------------------------------------
template <int TBN>
__global__ __launch_bounds__(512) void gemm_fused(const float* __restrict__ A,
                                                  const ushort* __restrict__ Wh,
                                                  const ushort* __restrict__ Wl,
                                                  ushort* __restrict__ Cb,
                                                  float* __restrict__ als,
                                                  float* __restrict__ ald,
                                                  const float* __restrict__ aS,
                                                  const float* __restrict__ aD,
                                                  int M) {
    constexpr int K = 256;
    constexpr int WN = TBN / 4;    // wave n-tile: 64 or 32
    constexpr int NF = WN / 16;    // n-frags per wave: 4 or 2
    __shared__ ushort Ah[128][40], Al[128][40];
    __shared__ ushort Bh[TBN][40], Bl[TBN][40];
    __shared__ float att_red[256];

    int tid = threadIdx.x;
    int wid = tid >> 6, lane = tid & 63;
    int wm = wid >> 2, wn = wid & 3;          // 2 x 4 wave grid
    int m0 = blockIdx.x * 128;

    f32x4 acc[4][NF];
#pragma unroll
    for (int i = 0; i < 4; i++)
#pragma unroll
        for (int j = 0; j < NF; j++) acc[i][j] = (f32x4){0.f, 0.f, 0.f, 0.f};

    for (int k0 = 0; k0 < K; k0 += 32) {
        // stage A tile (fp32 -> hi/lo): 128 rows x 8 float4 = 1024 slots
#pragma unroll
        for (int i = 0; i < 2; i++) {
            int s = tid + 512 * i;
            int r = s >> 3, c4 = s & 7;
            float4 v = make_float4(0.f, 0.f, 0.f, 0.f);
            if (m0 + r < M) v = *(const float4*)(A + (size_t)(m0 + r) * K + k0 + c4 * 4);
            ushort4 hi, lo;
            hi.x = f2bf(v.x); lo.x = f2bf(v.x - bf2f(hi.x));
            hi.y = f2bf(v.y); lo.y = f2bf(v.y - bf2f(hi.y));
            hi.z = f2bf(v.z); lo.z = f2bf(v.z - bf2f(hi.z));
            hi.w = f2bf(v.w); lo.w = f2bf(v.w - bf2f(hi.w));
            *(ushort4*)&Ah[r][c4 * 4] = hi;
            *(ushort4*)&Al[r][c4 * 4] = lo;
        }
        // stage B tile from pre-split planes: 16 ushorts per slot per plane
        if constexpr (TBN == 256) {
            int r = tid >> 1, c16 = (tid & 1) * 16;
            const ushort* gh = Wh + (size_t)r * K + k0 + c16;
            const ushort* gl = Wl + (size_t)r * K + k0 + c16;
            *(ushort8_t*)&Bh[r][c16]     = *(const ushort8_t*)gh;
            *(ushort8_t*)&Bh[r][c16 + 8] = *(const ushort8_t*)(gh + 8);
            *(ushort8_t*)&Bl[r][c16]     = *(const ushort8_t*)gl;
            *(ushort8_t*)&Bl[r][c16 + 8] = *(const ushort8_t*)(gl + 8);
        } else {
            int s = tid & 255;
            int r = s >> 1, c16 = (s & 1) * 16;
            const ushort* gp = ((tid < 256) ? Wh : Wl) + (size_t)r * K + k0 + c16;
            ushort* lp = ((tid < 256) ? &Bh[r][c16] : &Bl[r][c16]);
            *(ushort8_t*)lp       = *(const ushort8_t*)gp;
            *(ushort8_t*)(lp + 8) = *(const ushort8_t*)(gp + 8);
        }
        __syncthreads();

        int koff = (lane >> 4) * 8;          // k-offset within BK=32
        int rsel = lane & 15;
        bf16x8 ah[4], al[4], bh[NF], bl[NF];
#pragma unroll
        for (int mf = 0; mf < 4; mf++) {
            int r = wm * 64 + mf * 16 + rsel;
            ah[mf] = *(const bf16x8*)&Ah[r][koff];
            al[mf] = *(const bf16x8*)&Al[r][koff];
        }
#pragma unroll
        for (int nf = 0; nf < NF; nf++) {
            int c = wn * WN + nf * 16 + rsel;
            bh[nf] = *(const bf16x8*)&Bh[c][koff];
            bl[nf] = *(const bf16x8*)&Bl[c][koff];
        }
#pragma unroll
        for (int mf = 0; mf < 4; mf++)
#pragma unroll
            for (int nf = 0; nf < NF; nf++) {
                acc[mf][nf] = __builtin_amdgcn_mfma_f32_16x16x32_bf16(ah[mf], bh[nf], acc[mf][nf], 0, 0, 0);
                acc[mf][nf] = __builtin_amdgcn_mfma_f32_16x16x32_bf16(ah[mf], bl[nf], acc[mf][nf], 0, 0, 0);
                acc[mf][nf] = __builtin_amdgcn_mfma_f32_16x16x32_bf16(al[mf], bh[nf], acc[mf][nf], 0, 0, 0);
            }
        __syncthreads();
    }

    int l15 = lane & 15, lhi = lane >> 4;

    // bf16 C store (C/D layout: col = lane&15, row = (lane>>4)*4 + j)
#pragma unroll
    for (int mf = 0; mf < 4; mf++) {
        int gr0 = m0 + wm * 64 + mf * 16 + lhi * 4;
#pragma unroll
        for (int nf = 0; nf < NF; nf++) {
            int gc = wn * WN + nf * 16 + l15;
#pragma unroll
            for (int j = 0; j < 4; j++)
                if (gr0 + j < M) Cb[(size_t)(gr0 + j) * TBN + gc] = f2bf(acc[mf][nf][j]);
        }
    }

    // fused attention logits from fp32 acc
    if constexpr (TBN == 256) {
        float as0 = aS[wn * 64 + l15],      as0b = aS[wn * 64 + 16 + l15];
        float as1 = aS[wn * 64 + 32 + l15], as1b = aS[wn * 64 + 48 + l15];
        float ad0 = aD[wn * 64 + l15],      ad0b = aD[wn * 64 + 16 + l15];
        float ad1 = aD[wn * 64 + 32 + l15], ad1b = aD[wn * 64 + 48 + l15];
#pragma unroll
        for (int mf = 0; mf < 4; mf++) {
#pragma unroll
            for (int j = 0; j < 4; j++) {
                float ps0 = acc[mf][0][j] * as0 + acc[mf][1][j] * as0b;
                float ps1 = acc[mf][2][j] * as1 + acc[mf][3][j] * as1b;
                float pd0 = acc[mf][0][j] * ad0 + acc[mf][1][j] * ad0b;
                float pd1 = acc[mf][2][j] * ad1 + acc[mf][3][j] * ad1b;
#pragma unroll
                for (int off = 1; off <= 8; off <<= 1) {
                    ps0 += __shfl_xor(ps0, off, 64);
                    ps1 += __shfl_xor(ps1, off, 64);
                    pd0 += __shfl_xor(pd0, off, 64);
                    pd1 += __shfl_xor(pd1, off, 64);
                }
                int gr = m0 + wm * 64 + mf * 16 + lhi * 4 + j;
                if (l15 == 0 && gr < M) {
                    als[gr * 8 + 2 * wn]     = ps0;
                    als[gr * 8 + 2 * wn + 1] = ps1;
                    ald[gr * 8 + 2 * wn]     = pd0;
                    ald[gr * 8 + 2 * wn + 1] = pd1;
                }
            }
        }
    } else {
        // single head over 128 cols; cross-wave reduce via LDS
        float asv0 = aS[wn * 32 + l15], asv1 = aS[wn * 32 + 16 + l15];
        float adv0 = aD[wn * 32 + l15], adv1 = aD[wn * 32 + 16 + l15];
        if (tid < 256) att_red[tid] = 0.f;
        __syncthreads();
#pragma unroll
        for (int mf = 0; mf < 4; mf++) {
#pragma unroll
            for (int j = 0; j < 4; j++) {
                float ps = acc[mf][0][j] * asv0 + acc[mf][1][j] * asv1;
                float pd = acc[mf][0][j] * adv0 + acc[mf][1][j] * adv1;
#pragma unroll
                for (int off = 1; off <= 8; off <<= 1) {
                    ps += __shfl_xor(ps, off, 64);
                    pd += __shfl_xor(pd, off, 64);
                }
                if (l15 == 0) {
                    int rl = wm * 64 + mf * 16 + lhi * 4 + j;
                    atomicAdd(&att_red[rl], ps);
                    atomicAdd(&att_red[128 + rl], pd);
                }
            }
        }
        __syncthreads();
        if (tid < 128 && m0 + tid < M) {
            als[m0 + tid] = att_red[tid];
            ald[m0 + tid] = att_red[128 + tid];
        }
    }
}

// ---------------------------------------------------------------------------
// Layer 1 aggregation (round-5 verified): 128 thr, 2 waves; thread owns comps
// 2*tid, 2*tid+1. Full 16-edge chunks unrolled & wave-uniform; runtime tail.
// ---------------------------------------------------------------------------
__global__ __launch_bounds__(128) void k_agg1(
    const ushort* __restrict__ h1b, const float* __restrict__ als,
    const float* __restrict__ ald, const int* __restrict__ offsets,
    const int* __restrict__ srcs, const float* __restrict__ b1,
    float* __restrict__ out1) {
    int n = blockIdx.x;
    int tid = threadIdx.x;            // 0..127
    int lane = tid & 63;
    int wv = tid >> 6;                // wave id 0/1
    int hl = lane >> 4;               // local head 0..3 (global head = wv*4+hl)
    int base = offsets[n], deg = offsets[n + 1] - base;

    // stage roles: edge eL = lane>>2 (0..15), head hS = wv*4 + (lane&3)
    int eL = lane >> 2;
    int hS = wv * 4 + (lane & 3);
    float aldS = ald[n * 8 + hS];

    float acc0 = 0.f, acc1 = 0.f, dsum = 0.f;
    int chunk = 0;
    for (; chunk + 16 <= deg; chunk += 16) {        // full chunks: uniform, unrolled
        int sE = srcs[base + chunk + eL];
        float v = als[sE * 8 + hS] + aldS;
        v = (v >= 0.f) ? v : 0.2f * v;
        float wE = __expf(v);
#pragma unroll
        for (int i = 0; i < 16; i++) {
            int si = __shfl(sE, i * 4, 64);
            float wi = __shfl(wE, i * 4 + hl, 64);
            unsigned u = *(const unsigned*)(h1b + (size_t)si * 256 + 2 * tid);
            acc0 += wi * bflo(u);
            acc1 += wi * bfhi(u);
            dsum += wi;
        }
    }
    if (chunk < deg) {                               // tail: runtime loop
        int len = deg - chunk;                       // 1..15, wave-uniform
        int idx = chunk + eL; if (idx >= deg) idx = deg - 1;
        int sE = srcs[base + idx];
        float v = als[sE * 8 + hS] + aldS;
        v = (v >= 0.f) ? v : 0.2f * v;
        float wE = __expf(v);
        for (int i = 0; i < len; i++) {
            int si = __shfl(sE, i * 4, 64);
            float wi = __shfl(wE, i * 4 + hl, 64);
            unsigned u = *(const unsigned*)(h1b + (size_t)si * 256 + 2 * tid);
            acc0 += wi * bflo(u);
            acc1 += wi * bfhi(u);
            dsum += wi;
        }
    }
    float inv = 1.f / (dsum + 1e-16f);
    float r0 = acc0 * inv + b1[2 * tid];
    float r1 = acc1 * inv + b1[2 * tid + 1];
    r0 = (r0 >= 0.f) ? r0 : 0.2f * r0;   // module LeakyReLU
    r1 = (r1 >= 0.f) ? r1 : 0.2f * r1;
    *(float2*)(out1 + (size_t)n * 256 + 2 * tid) = make_float2(r0, r1);
}

// ---------------------------------------------------------------------------
// Layer 2 aggregation (round-5 verified): 1 wave, thread owns comps 2*lane,
// 2*lane+1; 16-edge chunks staged via lane&15, unrolled; runtime tail.
// ---------------------------------------------------------------------------
__global__ __launch_bounds__(64) void k_agg2(
    const ushort* __restrict__ h2b, const float* __restrict__ als,
    const float* __restrict__ ald, const int* __restrict__ offsets,
    const int* __restrict__ srcs, const float* __restrict__ b2,
    float* __restrict__ out) {
    int n = blockIdx.x;
    int lane = threadIdx.x;           // 0..63
    int l16 = lane & 15;              // staged edge slot
    int base = offsets[n], deg = offsets[n + 1] - base;
    float aldv = ald[n];

    float acc0 = 0.f, acc1 = 0.f, dsum = 0.f;
    int chunk = 0;
    for (; chunk + 16 <= deg; chunk += 16) {        // full chunks: uniform, unrolled
        int sE = srcs[base + chunk + l16];
        float v = als[sE] + aldv;
        v = (v >= 0.f) ? v : 0.2f * v;
        float wE = __expf(v);
#pragma unroll
        for (int i = 0; i < 16; i++) {
            int si = __shfl(sE, i, 64);
            float wi = __shfl(wE, i, 64);
            unsigned u = *(const unsigned*)(h2b + (size_t)si * 128 + 2 * lane);
            acc0 += wi * bflo(u);
            acc1 += wi * bfhi(u);
            dsum += wi;
        }
    }
    if (chunk < deg) {                               // tail
        int len = deg - chunk;                       // 1..15, wave-uniform
        int idx = chunk + l16; if (idx >= deg) idx = deg - 1;
        int sE = srcs[base + idx];
        float v = als[sE] + aldv;
        v = (v >= 0.f) ? v : 0.2f * v;
        float wE = __expf(v);
        for (int i = 0; i < len; i++) {
            int si = __shfl(sE, i, 64);
            float wi = __shfl(wE, i, 64);
            unsigned u = *(const unsigned*)(h2b + (size_t)si * 128 + 2 * lane);
            acc0 += wi * bflo(u);
            acc1 += wi * bfhi(u);
            dsum += wi;
        }
    }
    float inv = 1.f / (dsum + 1e-16f);
    *(float2*)(out + (size_t)n * 128 + 2 * lane) =
        make_float2(acc0 * inv + b2[2 * lane], acc1 * inv + b2[2 * lane + 1]);
}

// ---------------------------------------------------------------------------
extern "C" void kernel_launch(void* const* d_in, const int* in_sizes, int n_in,
                              void* d_out, int out_size, void* d_ws, size_t ws_size,
                              hipStream_t stream) {
    const int* ei = (const int*)d_in[0];         // [2, EE] int32
    const float* x = (const float*)d_in[1];      // [N, 256]
    const float* W1 = (const float*)d_in[2];     // [256, 256]
    const float* aS1 = (const float*)d_in[3];    // [8, 32]
    const float* aD1 = (const float*)d_in[4];    // [8, 32]
    const float* b1 = (const float*)d_in[5];     // [256]
    const float* W2 = (const float*)d_in[6];     // [128, 256]
    const float* aS2 = (const float*)d_in[7];    // [1, 128]
    const float* aD2 = (const float*)d_in[8];    // [1, 128]
    const float* b2 = (const float*)d_in[9];     // [128]
    float* out = (float*)d_out;

    char* w = (char*)d_ws;
    auto alloc = [&](size_t bytes) {
        char* p = w;
        w += (bytes + 255) & ~(size_t)255;
        return p;
    };
    ushort* h1b  = (ushort*)alloc((size_t)NN * 256 * 2);  // reused as h2b
    float*  out1 = (float*)alloc((size_t)NN * 256 * 4);
    float*  als1 = (float*)alloc((size_t)NN * 8 * 4);     // reused as als2
    float*  ald1 = (float*)alloc((size_t)NN * 8 * 4);     // reused as ald2
    int* deg     = (int*)alloc((size_t)(NN + 1) * 4);
    int* offsets = (int*)alloc((size_t)(NN + 1) * 4);
    int* cursor  = (int*)alloc((size_t)NN * 4);
    int* srcs    = (int*)alloc((size_t)ET * 4);
    int* bsum    = (int*)alloc(64 * 4);
    ushort* W1h  = (ushort*)alloc((size_t)256 * 256 * 2);
    ushort* W1l  = (ushort*)alloc((size_t)256 * 256 * 2);
    ushort* W2h  = (ushort*)alloc((size_t)128 * 256 * 2);
    ushort* W2l  = (ushort*)alloc((size_t)128 * 256 * 2);
    ushort* h2b = h1b;
    float* als2 = als1;
    float* ald2 = ald1;

    const int nb = (NN + 1023) / 1024;

    hipMemsetAsync(deg, 0, (size_t)NN * 4, stream);
    hipMemsetAsync(cursor, 0, (size_t)NN * 4, stream);

    // weight pre-split (tiny)
    k_splitW<<<(256 * 256 + 255) / 256, 256, 0, stream>>>(W1, W1h, W1l, 256 * 256);
    k_splitW<<<(128 * 256 + 255) / 256, 256, 0, stream>>>(W2, W2h, W2l, 128 * 256);

    // CSR build
    k_hist<<<(ET + 255) / 256, 256, 0, stream>>>(ei, deg);
    k_scan_block<<<nb, 1024, 0, stream>>>(deg, offsets, bsum, NN);
    k_scan_bsums<<<1, 64, 0, stream>>>(bsum, nb);
    k_add_off<<<(NN + 255) / 256, 256, 0, stream>>>(offsets, bsum, NN, ET);
    k_scatter<<<(ET + 255) / 256, 256, 0, stream>>>(ei, offsets, cursor, srcs);

    // Layer 1: GEMM + fused logits, then aggregate
    gemm_fused<256><<<(NN + 127) / 128, 512, 0, stream>>>(x, W1h, W1l, h1b, als1, ald1, aS1, aD1, NN);
    k_agg1<<<NN, 128, 0, stream>>>(h1b, als1, ald1, offsets, srcs, b1, out1);

    // Layer 2: GEMM + fused logits, then aggregate
    gemm_fused<128><<<(NN + 127) / 128, 512, 0, stream>>>(out1, W2h, W2l, h2b, als2, ald2, aS2, aD2, NN);
    k_agg2<<<NN, 64, 0, stream>>>(h2b, als2, ald2, offsets, srcs, b2, out);
}

// Round 8
// 271.259 us; speedup vs baseline: 2.1741x; 1.0846x over previous
//
#include <hip/hip_runtime.h>
#include <hip/hip_bf16.h>
#include <math.h>

// Problem constants (from reference)
#define NN 50000
#define EE 800000
#define ET 850000   // EE + NN self loops
#define NFEATS 256
#define NHIDS 32
#define NHEADS 8
#define NOUT 128

typedef __attribute__((ext_vector_type(8))) short bf16x8;
typedef __attribute__((ext_vector_type(4))) float f32x4;
typedef __attribute__((ext_vector_type(8))) unsigned short ushort8_t;

__device__ inline ushort f2bf(float x) {
    __hip_bfloat16 b = __float2bfloat16(x);   // RTN
    return *reinterpret_cast<ushort*>(&b);
}
__device__ inline float bf2f(ushort u) {
    unsigned v = ((unsigned)u) << 16;
    return __builtin_bit_cast(float, v);
}
__device__ inline float bflo(unsigned u) {
    return __builtin_bit_cast(float, u << 16);
}
__device__ inline float bfhi(unsigned u) {
    return __builtin_bit_cast(float, u & 0xffff0000u);
}

// ---------------------------------------------------------------------------
// CSR build: histogram -> scan -> scatter (stores SRC id directly)
// ---------------------------------------------------------------------------
__global__ void k_hist(const int* __restrict__ ei, int* __restrict__ deg) {
    int e = blockIdx.x * blockDim.x + threadIdx.x;
    if (e >= ET) return;
    int d = (e < EE) ? ei[EE + e] : (e - EE);
    atomicAdd(&deg[d], 1);
}

__global__ void k_scan_block(const int* __restrict__ deg, int* __restrict__ offsets,
                             int* __restrict__ bsum, int n) {
    __shared__ int lds[1024];
    int i = blockIdx.x * 1024 + threadIdx.x;
    int v = (i < n) ? deg[i] : 0;
    lds[threadIdx.x] = v;
    __syncthreads();
    for (int off = 1; off < 1024; off <<= 1) {
        int t = 0;
        if ((int)threadIdx.x >= off) t = lds[threadIdx.x - off];
        __syncthreads();
        lds[threadIdx.x] += t;
        __syncthreads();
    }
    if (i < n) offsets[i] = lds[threadIdx.x] - v;   // exclusive within block
    if (threadIdx.x == 1023) bsum[blockIdx.x] = lds[1023];
}

__global__ void k_scan_bsums(int* __restrict__ bsum, int nb) {
    int t = threadIdx.x;                 // single block, 64 threads, nb <= 64
    int v0 = (t < nb) ? bsum[t] : 0;
    int v = v0;
    for (int off = 1; off < 64; off <<= 1) {
        int u = __shfl_up(v, off, 64);
        if (t >= off) v += u;
    }
    if (t < nb) bsum[t] = v - v0;        // exclusive block offsets
}

__global__ void k_add_off(int* __restrict__ offsets, const int* __restrict__ bsum,
                          int n, int total) {
    int i = blockIdx.x * blockDim.x + threadIdx.x;
    if (i < n) offsets[i] += bsum[i >> 10];
    if (i == 0) offsets[n] = total;
}

__global__ void k_scatter(const int* __restrict__ ei, const int* __restrict__ offsets,
                          int* __restrict__ cursor, int* __restrict__ srcs) {
    int e = blockIdx.x * blockDim.x + threadIdx.x;
    if (e >= ET) return;
    int d, s;
    if (e < EE) { d = ei[EE + e]; s = ei[e]; }
    else        { d = e - EE;     s = e - EE; }
    int pos = offsets[d] + atomicAdd(&cursor[d], 1);
    srcs[pos] = s;
}

// ---------------------------------------------------------------------------
// Weight pre-split: fp32 -> (hi, lo) bf16 planes, done once per call.
// ---------------------------------------------------------------------------
__global__ void k_splitW(const float* __restrict__ W, ushort* __restrict__ Wh,
                         ushort* __restrict__ Wl, int n) {
    int i = blockIdx.x * blockDim.x + threadIdx.x;
    if (i >= n) return;
    float v = W[i];
    ushort h = f2bf(v);
    Wh[i] = h;
    Wl[i] = f2bf(v - bf2f(h));
}

// ---------------------------------------------------------------------------
// bf16x3 MFMA GEMM with fused attention-logit epilogue (round-7 verified).
// ---------------------------------------------------------------------------
template <int TBN>
__global__ __launch_bounds__(512) void gemm_fused(const float* __restrict__ A,
                                                  const ushort* __restrict__ Wh,
                                                  const ushort* __restrict__ Wl,
                                                  ushort* __restrict__ Cb,
                                                  float* __restrict__ als,
                                                  float* __restrict__ ald,
                                                  const float* __restrict__ aS,
                                                  const float* __restrict__ aD,
                                                  int M) {
    constexpr int K = 256;
    constexpr int WN = TBN / 4;    // wave n-tile: 64 or 32
    constexpr int NF = WN / 16;    // n-frags per wave: 4 or 2
    __shared__ ushort Ah[128][40], Al[128][40];
    __shared__ ushort Bh[TBN][40], Bl[TBN][40];
    __shared__ float att_red[256];

    int tid = threadIdx.x;
    int wid = tid >> 6, lane = tid & 63;
    int wm = wid >> 2, wn = wid & 3;          // 2 x 4 wave grid
    int m0 = blockIdx.x * 128;

    f32x4 acc[4][NF];
#pragma unroll
    for (int i = 0; i < 4; i++)
#pragma unroll
        for (int j = 0; j < NF; j++) acc[i][j] = (f32x4){0.f, 0.f, 0.f, 0.f};

    for (int k0 = 0; k0 < K; k0 += 32) {
        // stage A tile (fp32 -> hi/lo): 128 rows x 8 float4 = 1024 slots
#pragma unroll
        for (int i = 0; i < 2; i++) {
            int s = tid + 512 * i;
            int r = s >> 3, c4 = s & 7;
            float4 v = make_float4(0.f, 0.f, 0.f, 0.f);
            if (m0 + r < M) v = *(const float4*)(A + (size_t)(m0 + r) * K + k0 + c4 * 4);
            ushort4 hi, lo;
            hi.x = f2bf(v.x); lo.x = f2bf(v.x - bf2f(hi.x));
            hi.y = f2bf(v.y); lo.y = f2bf(v.y - bf2f(hi.y));
            hi.z = f2bf(v.z); lo.z = f2bf(v.z - bf2f(hi.z));
            hi.w = f2bf(v.w); lo.w = f2bf(v.w - bf2f(hi.w));
            *(ushort4*)&Ah[r][c4 * 4] = hi;
            *(ushort4*)&Al[r][c4 * 4] = lo;
        }
        // stage B tile from pre-split planes: 16 ushorts per slot per plane
        if constexpr (TBN == 256) {
            int r = tid >> 1, c16 = (tid & 1) * 16;
            const ushort* gh = Wh + (size_t)r * K + k0 + c16;
            const ushort* gl = Wl + (size_t)r * K + k0 + c16;
            *(ushort8_t*)&Bh[r][c16]     = *(const ushort8_t*)gh;
            *(ushort8_t*)&Bh[r][c16 + 8] = *(const ushort8_t*)(gh + 8);
            *(ushort8_t*)&Bl[r][c16]     = *(const ushort8_t*)gl;
            *(ushort8_t*)&Bl[r][c16 + 8] = *(const ushort8_t*)(gl + 8);
        } else {
            int s = tid & 255;
            int r = s >> 1, c16 = (s & 1) * 16;
            const ushort* gp = ((tid < 256) ? Wh : Wl) + (size_t)r * K + k0 + c16;
            ushort* lp = ((tid < 256) ? &Bh[r][c16] : &Bl[r][c16]);
            *(ushort8_t*)lp       = *(const ushort8_t*)gp;
            *(ushort8_t*)(lp + 8) = *(const ushort8_t*)(gp + 8);
        }
        __syncthreads();

        int koff = (lane >> 4) * 8;          // k-offset within BK=32
        int rsel = lane & 15;
        bf16x8 ah[4], al[4], bh[NF], bl[NF];
#pragma unroll
        for (int mf = 0; mf < 4; mf++) {
            int r = wm * 64 + mf * 16 + rsel;
            ah[mf] = *(const bf16x8*)&Ah[r][koff];
            al[mf] = *(const bf16x8*)&Al[r][koff];
        }
#pragma unroll
        for (int nf = 0; nf < NF; nf++) {
            int c = wn * WN + nf * 16 + rsel;
            bh[nf] = *(const bf16x8*)&Bh[c][koff];
            bl[nf] = *(const bf16x8*)&Bl[c][koff];
        }
#pragma unroll
        for (int mf = 0; mf < 4; mf++)
#pragma unroll
            for (int nf = 0; nf < NF; nf++) {
                acc[mf][nf] = __builtin_amdgcn_mfma_f32_16x16x32_bf16(ah[mf], bh[nf], acc[mf][nf], 0, 0, 0);
                acc[mf][nf] = __builtin_amdgcn_mfma_f32_16x16x32_bf16(ah[mf], bl[nf], acc[mf][nf], 0, 0, 0);
                acc[mf][nf] = __builtin_amdgcn_mfma_f32_16x16x32_bf16(al[mf], bh[nf], acc[mf][nf], 0, 0, 0);
            }
        __syncthreads();
    }

    int l15 = lane & 15, lhi = lane >> 4;

    // bf16 C store (C/D layout: col = lane&15, row = (lane>>4)*4 + j)
#pragma unroll
    for (int mf = 0; mf < 4; mf++) {
        int gr0 = m0 + wm * 64 + mf * 16 + lhi * 4;
#pragma unroll
        for (int nf = 0; nf < NF; nf++) {
            int gc = wn * WN + nf * 16 + l15;
#pragma unroll
            for (int j = 0; j < 4; j++)
                if (gr0 + j < M) Cb[(size_t)(gr0 + j) * TBN + gc] = f2bf(acc[mf][nf][j]);
        }
    }

    // fused attention logits from fp32 acc
    if constexpr (TBN == 256) {
        float as0 = aS[wn * 64 + l15],      as0b = aS[wn * 64 + 16 + l15];
        float as1 = aS[wn * 64 + 32 + l15], as1b = aS[wn * 64 + 48 + l15];
        float ad0 = aD[wn * 64 + l15],      ad0b = aD[wn * 64 + 16 + l15];
        float ad1 = aD[wn * 64 + 32 + l15], ad1b = aD[wn * 64 + 48 + l15];
#pragma unroll
        for (int mf = 0; mf < 4; mf++) {
#pragma unroll
            for (int j = 0; j < 4; j++) {
                float ps0 = acc[mf][0][j] * as0 + acc[mf][1][j] * as0b;
                float ps1 = acc[mf][2][j] * as1 + acc[mf][3][j] * as1b;
                float pd0 = acc[mf][0][j] * ad0 + acc[mf][1][j] * ad0b;
                float pd1 = acc[mf][2][j] * ad1 + acc[mf][3][j] * ad1b;
#pragma unroll
                for (int off = 1; off <= 8; off <<= 1) {
                    ps0 += __shfl_xor(ps0, off, 64);
                    ps1 += __shfl_xor(ps1, off, 64);
                    pd0 += __shfl_xor(pd0, off, 64);
                    pd1 += __shfl_xor(pd1, off, 64);
                }
                int gr = m0 + wm * 64 + mf * 16 + lhi * 4 + j;
                if (l15 == 0 && gr < M) {
                    als[gr * 8 + 2 * wn]     = ps0;
                    als[gr * 8 + 2 * wn + 1] = ps1;
                    ald[gr * 8 + 2 * wn]     = pd0;
                    ald[gr * 8 + 2 * wn + 1] = pd1;
                }
            }
        }
    } else {
        // single head over 128 cols; cross-wave reduce via LDS
        float asv0 = aS[wn * 32 + l15], asv1 = aS[wn * 32 + 16 + l15];
        float adv0 = aD[wn * 32 + l15], adv1 = aD[wn * 32 + 16 + l15];
        if (tid < 256) att_red[tid] = 0.f;
        __syncthreads();
#pragma unroll
        for (int mf = 0; mf < 4; mf++) {
#pragma unroll
            for (int j = 0; j < 4; j++) {
                float ps = acc[mf][0][j] * asv0 + acc[mf][1][j] * asv1;
                float pd = acc[mf][0][j] * adv0 + acc[mf][1][j] * adv1;
#pragma unroll
                for (int off = 1; off <= 8; off <<= 1) {
                    ps += __shfl_xor(ps, off, 64);
                    pd += __shfl_xor(pd, off, 64);
                }
                if (l15 == 0) {
                    int rl = wm * 64 + mf * 16 + lhi * 4 + j;
                    atomicAdd(&att_red[rl], ps);
                    atomicAdd(&att_red[128 + rl], pd);
                }
            }
        }
        __syncthreads();
        if (tid < 128 && m0 + tid < M) {
            als[m0 + tid] = att_red[tid];
            ald[m0 + tid] = att_red[128 + tid];
        }
    }
}

// ---------------------------------------------------------------------------
// Layer 1 aggregation v2: 128 thr = 2 independent waves = 2 nodes/block.
// 16B (uint4) gathers: 32 lanes cover one 512B h1-row; half-wave g in {0,1}
// processes edges e = 2i+g. Chunk of 16 edges dual-staged (eL8 = lane>>3,
// hS = lane&7, all 8 heads). SINGLE wave-uniform body: all shfls executed
// unconditionally; out-of-range edges masked by wi = 0 on a clamped
// (already-cached) row. No guarded shfls, no divergent loops.
// ---------------------------------------------------------------------------
__global__ __launch_bounds__(128) void k_agg1(
    const ushort* __restrict__ h1b, const float* __restrict__ als,
    const float* __restrict__ ald, const int* __restrict__ offsets,
    const int* __restrict__ srcs, const float* __restrict__ b1,
    float* __restrict__ out1) {
    int lane = threadIdx.x & 63;
    int wv = threadIdx.x >> 6;
    int n = blockIdx.x * 2 + wv;
    int g = lane >> 5;                // edge parity slot (0/1)
    int c32 = lane & 31;              // 16B slot within row: comps [8*c32, 8*c32+8)
    int head = c32 >> 2;              // head of owned comps
    int base = offsets[n], deg = offsets[n + 1] - base;

    int eL8 = lane >> 3;              // staged edge 0..7
    int hS = lane & 7;                // staged head
    float aldS = ald[n * 8 + hS];

    float acc[8] = {0.f, 0.f, 0.f, 0.f, 0.f, 0.f, 0.f, 0.f};
    float dsum = 0.f;
    for (int chunk = 0; chunk < deg; chunk += 16) {
        int len = deg - chunk; if (len > 16) len = 16;
        int i0 = chunk + eL8;     if (i0 >= deg) i0 = deg - 1;
        int i1 = chunk + 8 + eL8; if (i1 >= deg) i1 = deg - 1;
        int sE0 = srcs[base + i0];
        int sE1 = srcs[base + i1];
        float v0 = als[sE0 * 8 + hS] + aldS;
        float v1 = als[sE1 * 8 + hS] + aldS;
        v0 = (v0 >= 0.f) ? v0 : 0.2f * v0;
        v1 = (v1 >= 0.f) ? v1 : 0.2f * v1;
        float w0 = __expf(v0), w1 = __expf(v1);
#pragma unroll
        for (int i = 0; i < 8; i++) {
            int e = 2 * i + g;                     // 0..15
            int slot = (e & 7) * 8;                // staging lane group base
            int si = __shfl((i < 4) ? sE0 : sE1, slot, 64);
            float wi = __shfl((i < 4) ? w0 : w1, slot + head, 64);
            if (e >= len) wi = 0.f;                // mask dummy edges
            uint4 hv = *(const uint4*)(h1b + (size_t)si * 256 + 8 * c32);
            acc[0] += wi * bflo(hv.x); acc[1] += wi * bfhi(hv.x);
            acc[2] += wi * bflo(hv.y); acc[3] += wi * bfhi(hv.y);
            acc[4] += wi * bflo(hv.z); acc[5] += wi * bfhi(hv.z);
            acc[6] += wi * bflo(hv.w); acc[7] += wi * bfhi(hv.w);
            dsum += wi;
        }
    }
    // combine the two half-wave edge streams
#pragma unroll
    for (int j = 0; j < 8; j++) acc[j] += __shfl_xor(acc[j], 32, 64);
    dsum += __shfl_xor(dsum, 32, 64);

    if (g == 0) {
        float inv = 1.f / (dsum + 1e-16f);
        const float* bb = b1 + 8 * c32;
        float r[8];
#pragma unroll
        for (int j = 0; j < 8; j++) {
            float t = acc[j] * inv + bb[j];
            r[j] = (t >= 0.f) ? t : 0.2f * t;   // module LeakyReLU
        }
        float* o = out1 + (size_t)n * 256 + 8 * c32;
        *(float4*)o       = make_float4(r[0], r[1], r[2], r[3]);
        *(float4*)(o + 4) = make_float4(r[4], r[5], r[6], r[7]);
    }
}

// ---------------------------------------------------------------------------
// Layer 2 aggregation v2: 128 thr = 2 waves = 2 nodes/block. 16B gathers:
// 16 lanes cover one 256B h2-row; quarter-wave g in {0..3} processes edges
// e = 4i+g from a staged chunk of 16. Same uniform-body masking discipline.
// ---------------------------------------------------------------------------
__global__ __launch_bounds__(128) void k_agg2(
    const ushort* __restrict__ h2b, const float* __restrict__ als,
    const float* __restrict__ ald, const int* __restrict__ offsets,
    const int* __restrict__ srcs, const float* __restrict__ b2,
    float* __restrict__ out) {
    int lane = threadIdx.x & 63;
    int wv = threadIdx.x >> 6;
    int n = blockIdx.x * 2 + wv;
    int g = lane >> 4;                // edge slot (0..3)
    int c16 = lane & 15;              // 16B slot within row: comps [8*c16, 8*c16+8)
    int base = offsets[n], deg = offsets[n + 1] - base;
    float aldv = ald[n];

    float acc[8] = {0.f, 0.f, 0.f, 0.f, 0.f, 0.f, 0.f, 0.f};
    float dsum = 0.f;
    for (int chunk = 0; chunk < deg; chunk += 16) {
        int len = deg - chunk; if (len > 16) len = 16;
        int idx = chunk + c16; if (idx >= deg) idx = deg - 1;
        int sE = srcs[base + idx];
        float v = als[sE] + aldv;
        v = (v >= 0.f) ? v : 0.2f * v;
        float wE = __expf(v);
#pragma unroll
        for (int i = 0; i < 4; i++) {
            int e = 4 * i + g;                     // 0..15
            int si = __shfl(sE, e, 64);
            float wi = __shfl(wE, e, 64);
            if (e >= len) wi = 0.f;
            uint4 hv = *(const uint4*)(h2b + (size_t)si * 128 + 8 * c16);
            acc[0] += wi * bflo(hv.x); acc[1] += wi * bfhi(hv.x);
            acc[2] += wi * bflo(hv.y); acc[3] += wi * bfhi(hv.y);
            acc[4] += wi * bflo(hv.z); acc[5] += wi * bfhi(hv.z);
            acc[6] += wi * bflo(hv.w); acc[7] += wi * bfhi(hv.w);
            dsum += wi;
        }
    }
    // combine the four quarter-wave edge streams
#pragma unroll
    for (int j = 0; j < 8; j++) {
        acc[j] += __shfl_xor(acc[j], 16, 64);
        acc[j] += __shfl_xor(acc[j], 32, 64);
    }
    dsum += __shfl_xor(dsum, 16, 64);
    dsum += __shfl_xor(dsum, 32, 64);

    if (g == 0) {
        float inv = 1.f / (dsum + 1e-16f);
        const float* bb = b2 + 8 * c16;
        float r[8];
#pragma unroll
        for (int j = 0; j < 8; j++) r[j] = acc[j] * inv + bb[j];
        float* o = out + (size_t)n * 128 + 8 * c16;
        *(float4*)o       = make_float4(r[0], r[1], r[2], r[3]);
        *(float4*)(o + 4) = make_float4(r[4], r[5], r[6], r[7]);
    }
}

// ---------------------------------------------------------------------------
extern "C" void kernel_launch(void* const* d_in, const int* in_sizes, int n_in,
                              void* d_out, int out_size, void* d_ws, size_t ws_size,
                              hipStream_t stream) {
    const int* ei = (const int*)d_in[0];         // [2, EE] int32
    const float* x = (const float*)d_in[1];      // [N, 256]
    const float* W1 = (const float*)d_in[2];     // [256, 256]
    const float* aS1 = (const float*)d_in[3];    // [8, 32]
    const float* aD1 = (const float*)d_in[4];    // [8, 32]
    const float* b1 = (const float*)d_in[5];     // [256]
    const float* W2 = (const float*)d_in[6];     // [128, 256]
    const float* aS2 = (const float*)d_in[7];    // [1, 128]
    const float* aD2 = (const float*)d_in[8];    // [1, 128]
    const float* b2 = (const float*)d_in[9];     // [128]
    float* out = (float*)d_out;

    char* w = (char*)d_ws;
    auto alloc = [&](size_t bytes) {
        char* p = w;
        w += (bytes + 255) & ~(size_t)255;
        return p;
    };
    ushort* h1b  = (ushort*)alloc((size_t)NN * 256 * 2);  // reused as h2b
    float*  out1 = (float*)alloc((size_t)NN * 256 * 4);
    float*  als1 = (float*)alloc((size_t)NN * 8 * 4);     // reused as als2
    float*  ald1 = (float*)alloc((size_t)NN * 8 * 4);     // reused as ald2
    int* deg     = (int*)alloc((size_t)(NN + 1) * 4);
    int* offsets = (int*)alloc((size_t)(NN + 1) * 4);
    int* cursor  = (int*)alloc((size_t)NN * 4);
    int* srcs    = (int*)alloc((size_t)ET * 4);
    int* bsum    = (int*)alloc(64 * 4);
    ushort* W1h  = (ushort*)alloc((size_t)256 * 256 * 2);
    ushort* W1l  = (ushort*)alloc((size_t)256 * 256 * 2);
    ushort* W2h  = (ushort*)alloc((size_t)128 * 256 * 2);
    ushort* W2l  = (ushort*)alloc((size_t)128 * 256 * 2);
    ushort* h2b = h1b;
    float* als2 = als1;
    float* ald2 = ald1;

    const int nb = (NN + 1023) / 1024;

    hipMemsetAsync(deg, 0, (size_t)NN * 4, stream);
    hipMemsetAsync(cursor, 0, (size_t)NN * 4, stream);

    // weight pre-split (tiny)
    k_splitW<<<(256 * 256 + 255) / 256, 256, 0, stream>>>(W1, W1h, W1l, 256 * 256);
    k_splitW<<<(128 * 256 + 255) / 256, 256, 0, stream>>>(W2, W2h, W2l, 128 * 256);

    // CSR build
    k_hist<<<(ET + 255) / 256, 256, 0, stream>>>(ei, deg);
    k_scan_block<<<nb, 1024, 0, stream>>>(deg, offsets, bsum, NN);
    k_scan_bsums<<<1, 64, 0, stream>>>(bsum, nb);
    k_add_off<<<(NN + 255) / 256, 256, 0, stream>>>(offsets, bsum, NN, ET);
    k_scatter<<<(ET + 255) / 256, 256, 0, stream>>>(ei, offsets, cursor, srcs);

    // Layer 1: GEMM + fused logits, then aggregate (2 nodes per block)
    gemm_fused<256><<<(NN + 127) / 128, 512, 0, stream>>>(x, W1h, W1l, h1b, als1, ald1, aS1, aD1, NN);
    k_agg1<<<NN / 2, 128, 0, stream>>>(h1b, als1, ald1, offsets, srcs, b1, out1);

    // Layer 2: GEMM + fused logits, then aggregate (2 nodes per block)
    gemm_fused<128><<<(NN + 127) / 128, 512, 0, stream>>>(out1, W2h, W2l, h2b, als2, ald2, aS2, aD2, NN);
    k_agg2<<<NN / 2, 128, 0, stream>>>(h2b, als2, ald2, offsets, srcs, b2, out);
}